// Round 4
// baseline (1723.236 us; speedup 1.0000x reference)
//
#include <hip/hip_runtime.h>

#define TOK 4096
#define SEQ 512
#define BATCH 8
#define DIM 512
#define NHEAD 8
#define DK 64
#define FFD 2048

typedef unsigned short u16;
typedef unsigned int u32;
typedef float floatx4 __attribute__((ext_vector_type(4)));
typedef short shortx8 __attribute__((ext_vector_type(8)));

// epilogue mode bits
#define EP_RELU 1
#define EP_ACC  2
#define EP_F32  4
#define EP_PL   8
#define EP_QV  16

__device__ __forceinline__ u16 bfh(float f) {
    union { float f; unsigned u; } x; x.f = f;
    return (u16)((x.u + 0x7fffu + ((x.u >> 16) & 1u)) >> 16);
}
__device__ __forceinline__ float bff(u16 h) {
    union { unsigned u; float f; } x; x.u = (unsigned)h << 16; return x.f;
}
// truncation-based hi/lo split: residual ~2^-16 relative
__device__ __forceinline__ void bfsplit(float v, u16& h, u16& l) {
    union { float f; unsigned u; } x; x.f = v;
    union { unsigned u; float f; } hb; hb.u = x.u & 0xffff0000u;
    float rem = v - hb.f;
    union { float f; unsigned u; } rr; rr.f = rem;
    h = (u16)(x.u >> 16);
    l = (u16)(rr.u >> 16);
}
__device__ __forceinline__ float rec2(u16 h, u16 l) { return bff(h) + bff(l); }
__device__ __forceinline__ float wave_sum(float v) {
    #pragma unroll
    for (int off = 32; off; off >>= 1) v += __shfl_xor(v, off, 64);
    return v;
}

#define GLDS16(gp, lp) __builtin_amdgcn_global_load_lds( \
    (const __attribute__((address_space(1))) u32*)(const void*)(gp), \
    (__attribute__((address_space(3))) u32*)(void*)(lp), 16, 0, 0)

// sentinel: ws too small
__global__ void VAKT_52226802319686_kernel(float* out, int n) {
    int i = blockIdx.x * 256 + threadIdx.x;
    if (i < n) out[i] = 524288.f;
}

__global__ void embed_pl(const int* cd, const int* cad, const float* cemb,
                         const float* caemb,
                         u16* x0h, u16* x0l, u16* yh, u16* yl) {
    int tok = blockIdx.x;
    int idx = cd[tok];
    int resp = (cad[tok] - idx) / 1000;
    for (int d = threadIdx.x; d < DIM; d += 256) {
        float e = cemb[(size_t)idx * DIM + d];
        float yv = e + caemb[resp * DIM + d];
        size_t o = (size_t)tok * DIM + d;
        u16 hh, ll;
        bfsplit(e, hh, ll);  x0h[o] = hh; x0l[o] = ll;
        bfsplit(yv, hh, ll); yh[o] = hh;  yl[o] = ll;
    }
}

__global__ void concat_pl(const u16* Xh, const u16* Xl, const u16* X0h, const u16* X0l,
                          u16* Hh, u16* Hl) {
    int tok = blockIdx.x;
    for (int d = threadIdx.x; d < 2 * DIM; d += 256) {
        size_t s = (size_t)tok * DIM + ((d < DIM) ? d : d - DIM);
        size_t o = (size_t)tok * (2 * DIM) + d;
        Hh[o] = (d < DIM) ? Xh[s] : X0h[s];
        Hl[o] = (d < DIM) ? Xl[s] : X0l[s];
    }
}

// resid from planes + f32 delta -> LN -> planes out (in-place safe per-row)
__global__ void add_ln_pl(const u16* Xh, const u16* Xl, const float* Dl,
                          const float* sc, const float* bi, u16* Oh, u16* Ol) {
    int lane = threadIdx.x & 63, w = threadIdx.x >> 6;
    size_t row = (size_t)blockIdx.x * 4 + w;
    const u16* xh = Xh + row * DIM;
    const u16* xl = Xl + row * DIM;
    const float* dr = Dl + row * DIM;
    float v[8]; float sum = 0.f, sq = 0.f;
    for (int i = 0; i < 8; i++) {
        int d = i * 64 + lane;
        float t = rec2(xh[d], xl[d]) + dr[d];
        v[i] = t; sum += t; sq += t * t;
    }
    sum = wave_sum(sum); sq = wave_sum(sq);
    float mean = sum * (1.0f / 512.0f);
    float var = sq * (1.0f / 512.0f) - mean * mean;
    float rstd = rsqrtf(var + 1e-5f);
    for (int i = 0; i < 8; i++) {
        int d = i * 64 + lane;
        float val = (v[i] - mean) * rstd * sc[d] + bi[d];
        u16 hh, ll; bfsplit(val, hh, ll);
        Oh[row * DIM + d] = hh; Ol[row * DIM + d] = ll;
    }
}

// one 64x64 transpose+split tile: W[K][N] fp32 -> dst [Npad][K] u16 hi/lo
__device__ __forceinline__ void wtile_body(float (*T)[65], const float* W, int K, int N,
                                           int k0, int n0, u16* dh, u16* dl) {
    int t = threadIdx.x;
    for (int i = 0; i < 16; i++) {
        int idx = i * 256 + t;
        int kr = idx >> 6, nc = idx & 63;
        int gn = n0 + nc;
        T[kr][nc] = (gn < N) ? W[(size_t)(k0 + kr) * N + gn] : 0.f;
    }
    __syncthreads();
    for (int i = 0; i < 16; i++) {
        int idx = i * 256 + t;
        int nr = idx >> 6, kc = idx & 63;
        float v = T[kc][nr];
        u16 h = bfh(v);
        float rem = v - bff(h);
        size_t o = (size_t)(n0 + nr) * K + k0 + kc;
        dh[o] = h; dl[o] = bfh(rem);
    }
}

// all weight splits for one layer in a single launch.
// grid 192 (Wk,Wv,Wo) or 704 (+W1,W2)
__global__ __launch_bounds__(256) void wsplit_layer(
    const float* Wk, const float* Wv, const float* Wo,
    const float* W1, const float* W2,
    u16* qvh, u16* qvl, u16* woh, u16* wol,
    u16* w1h, u16* w1l, u16* w2h, u16* w2l) {
    __shared__ float T[64][65];
    int bid = blockIdx.x;
    if (bid < 192) {
        int m = bid >> 6, t2 = bid & 63;
        int k0 = (t2 & 7) * 64, n0 = (t2 >> 3) * 64;
        const float* W = (m == 0) ? Wk : (m == 1) ? Wv : Wo;
        u16* dh = (m == 0) ? qvh : (m == 1) ? (qvh + 512 * 512) : woh;
        u16* dl = (m == 0) ? qvl : (m == 1) ? (qvl + 512 * 512) : wol;
        wtile_body(T, W, 512, 512, k0, n0, dh, dl);
    } else if (bid < 448) {
        int t2 = bid - 192;
        wtile_body(T, W1, 512, 2048, (t2 & 7) * 64, (t2 >> 3) * 64, w1h, w1l);
    } else {
        int t2 = bid - 448;
        wtile_body(T, W2, 2048, 512, (t2 & 31) * 64, (t2 >> 5) * 64, w2h, w2l);
    }
}

// head weight splits: oW0 (1024x512), oW1 (512x1024), oW2 (1024x1000->pad1024). grid 512
__global__ __launch_bounds__(256) void wsplit_head(
    const float* oW0, const float* oW1, const float* oW2,
    u16* h0h, u16* h0l, u16* h1h, u16* h1l, u16* h2h, u16* h2l) {
    __shared__ float T[64][65];
    int bid = blockIdx.x;
    if (bid < 128) {
        wtile_body(T, oW0, 1024, 512, (bid & 15) * 64, (bid >> 4) * 64, h0h, h0l);
    } else if (bid < 256) {
        int t2 = bid - 128;
        wtile_body(T, oW1, 512, 1024, (t2 & 7) * 64, (t2 >> 3) * 64, h1h, h1l);
    } else {
        int t2 = bid - 256;
        wtile_body(T, oW2, 1024, 1000, (t2 & 15) * 64, (t2 >> 4) * 64, h2h, h2l);
    }
}

struct GD {
    const u16 *Ah, *Al, *Bh, *Bl;
    const float *bias, *bias2;
    float* Cf; u16 *Ch, *Cl, *Ch2, *Cl2;
    int K, Bstride, Boff, N, mode;
};

// C[4096,N] = A @ Bt^T (+bias). dual problem slots via blockIdx.z.
__global__ __launch_bounds__(256) void gemm_pp(GD d0, GD d1) {
    const GD d = blockIdx.z ? d1 : d0;
    const int bn0 = blockIdx.x * 64;
    if (bn0 >= ((d.N + 63) & ~63)) return;
    __shared__ u16 sm[24576];
    const int t = threadIdx.x;
    const int lane = t & 63, w = t >> 6;
    const int l16 = lane & 15, quad = lane >> 4;
    const int bm0 = blockIdx.y * 128;
    const int wm = (w & 1) * 64, wn = (w >> 1) * 32;

    floatx4 acc[4][2];
    #pragma unroll
    for (int mi = 0; mi < 4; mi++)
        #pragma unroll
        for (int ni = 0; ni < 2; ni++) acc[mi][ni] = (floatx4){0.f, 0.f, 0.f, 0.f};

    for (int k0 = 0; k0 < d.K; k0 += 64) {
        __syncthreads();
        #pragma unroll
        for (int p = 0; p < 2; ++p) {
            const u16* Asrc = p ? d.Al : d.Ah;
            #pragma unroll
            for (int rr = 0; rr < 4; ++rr) {
                int idx = (rr * 4 + w) * 64 + lane;
                int row = idx >> 3;
                int sg = (idx & 7) ^ (row & 7);
                const u16* gp = Asrc + (size_t)(bm0 + row) * d.K + k0 + sg * 8;
                u16* lp = sm + p * 8192 + (rr * 4 + w) * 512;
                GLDS16(gp, lp);
            }
        }
        #pragma unroll
        for (int p = 0; p < 2; ++p) {
            const u16* Bsrc = p ? d.Bl : d.Bh;
            #pragma unroll
            for (int rr = 0; rr < 2; ++rr) {
                int idx = (rr * 4 + w) * 64 + lane;
                int row = idx >> 3;
                int sg = (idx & 7) ^ (row & 7);
                const u16* gp = Bsrc + (size_t)(bn0 + row) * d.Bstride + d.Boff + k0 + sg * 8;
                u16* lp = sm + 16384 + p * 4096 + (rr * 4 + w) * 512;
                GLDS16(gp, lp);
            }
        }
        __syncthreads();
        #pragma unroll
        for (int ks = 0; ks < 2; ++ks) {
            shortx8 ah[4], al[4], bh2[2], bl2[2];
            #pragma unroll
            for (int mi = 0; mi < 4; ++mi) {
                int row = wm + mi * 16 + l16;
                int s = (ks * 4 + quad) ^ (row & 7);
                ah[mi] = *(const shortx8*)&sm[row * 64 + s * 8];
                al[mi] = *(const shortx8*)&sm[8192 + row * 64 + s * 8];
            }
            #pragma unroll
            for (int ni = 0; ni < 2; ++ni) {
                int row = wn + ni * 16 + l16;
                int s = (ks * 4 + quad) ^ (row & 7);
                bh2[ni] = *(const shortx8*)&sm[16384 + row * 64 + s * 8];
                bl2[ni] = *(const shortx8*)&sm[20480 + row * 64 + s * 8];
            }
            #pragma unroll
            for (int mi = 0; mi < 4; ++mi)
                #pragma unroll
                for (int ni = 0; ni < 2; ++ni) {
                    acc[mi][ni] = __builtin_amdgcn_mfma_f32_16x16x32_bf16(ah[mi], bh2[ni], acc[mi][ni], 0, 0, 0);
                    acc[mi][ni] = __builtin_amdgcn_mfma_f32_16x16x32_bf16(ah[mi], bl2[ni], acc[mi][ni], 0, 0, 0);
                    acc[mi][ni] = __builtin_amdgcn_mfma_f32_16x16x32_bf16(al[mi], bh2[ni], acc[mi][ni], 0, 0, 0);
                }
        }
    }
    #pragma unroll
    for (int ni = 0; ni < 2; ++ni) {
        int col = bn0 + wn + ni * 16 + l16;
        if (col < d.N) {
            float bv;
            if (d.mode & EP_ACC) bv = 0.f;
            else if ((d.mode & EP_QV) && col >= 512) bv = d.bias2[col - 512];
            else bv = d.bias[col];
            #pragma unroll
            for (int mi = 0; mi < 4; ++mi) {
                #pragma unroll
                for (int r = 0; r < 4; ++r) {
                    int row = bm0 + wm + mi * 16 + quad * 4 + r;
                    float v = acc[mi][ni][r] + bv;
                    if ((d.mode & EP_RELU) && v < 0.f) v = 0.f;
                    if (d.mode & EP_ACC) v += d.Cf[(size_t)row * d.N + col];
                    if (d.mode & EP_F32) d.Cf[(size_t)row * d.N + col] = v;
                    if (d.mode & EP_PL) {
                        u16 hh, ll; bfsplit(v, hh, ll);
                        if ((d.mode & EP_QV) && col >= 512) {
                            size_t o = (size_t)row * 512 + col - 512;
                            d.Ch2[o] = hh; d.Cl2[o] = ll;
                        } else {
                            size_t o = (size_t)row * ((d.mode & EP_QV) ? 512 : d.N) + col;
                            d.Ch[o] = hh; d.Cl[o] = ll;
                        }
                    }
                }
            }
        }
    }
}

// per-head transpose of pre-split V planes: vh/vl [4096][512] -> Vt[bh][64 d][512 s]
__global__ __launch_bounds__(256) void vtsplit_pp(const u16* __restrict__ vh,
                                                  const u16* __restrict__ vl,
                                                  u16* __restrict__ dh, u16* __restrict__ dl) {
    __shared__ u16 Th[64][72], Tl[64][72];
    const int t = threadIdx.x;
    const int s0 = blockIdx.x * 64;
    const int bh = blockIdx.y;
    const int b = bh >> 3, h = bh & 7;
    #pragma unroll
    for (int j = 0; j < 2; ++j) {
        int idx = j * 256 + t;
        int r = idx >> 3, sg = idx & 7;
        size_t src = (size_t)(b * SEQ + s0 + r) * DIM + h * 64 + sg * 8;
        *(uint4*)&Th[r][sg * 8] = *(const uint4*)(vh + src);
        *(uint4*)&Tl[r][sg * 8] = *(const uint4*)(vl + src);
    }
    __syncthreads();
    #pragma unroll
    for (int j = 0; j < 2; ++j) {
        int idx = j * 256 + t;
        int d = idx >> 3, sg = idx & 7;
        union { u16 e[8]; uint4 q; } xh, xl;
        #pragma unroll
        for (int k = 0; k < 8; ++k) { xh.e[k] = Th[sg * 8 + k][d]; xl.e[k] = Tl[sg * 8 + k][d]; }
        size_t dst = ((size_t)bh * 64 + d) * SEQ + s0 + sg * 8;
        *(uint4*)(dh + dst) = xh.q;
        *(uint4*)(dl + dst) = xl.q;
    }
}

// Barrier-free MFMA attention. One block = 64 q-rows of one (b,h), 4 waves x 16.
// All MFMA operands (Q,K,Vt) read directly from global (fragment layout == memory
// layout, L2-resident). P repack uses per-wave LDS only -> zero __syncthreads.
__global__ __launch_bounds__(256) void attn_mf(
    const u16* __restrict__ Qh, const u16* __restrict__ Ql,
    const u16* __restrict__ Kh, const u16* __restrict__ Kl,
    const u16* __restrict__ Vth, const u16* __restrict__ Vtl,
    const float* __restrict__ gam, u16* __restrict__ AOh, u16* __restrict__ AOl,
    int m0) {
    __shared__ __align__(16) u16 PB[4][2][16][72];
    const int t = threadIdx.x;
    const int lane = t & 63, w = t >> 6;
    const int l16 = lane & 15, quad = lane >> 4;
    const int chunk = 7 - (int)blockIdx.x;        // heavy blocks dispatch first
    const int h = blockIdx.y, b = blockIdx.z;
    const int bS = b * SEQ;
    const int bh = b * NHEAD + h;
    const int nch = chunk + 1, nkt = nch * 4;
    const int qrow0 = chunk * 64 + w * 16;
    const int qrow = qrow0 + l16;
    const int kmax = qrow - m0;

    float g = gam[h];
    float gamma = -((g > 20.f) ? g : log1pf(__expf(g)));

    shortx8 qh[2], ql[2];
    {
        const u16* qph = Qh + (size_t)(bS + qrow) * DIM + h * 64;
        const u16* qpl = Ql + (size_t)(bS + qrow) * DIM + h * 64;
        #pragma unroll
        for (int ks = 0; ks < 2; ++ks) {
            qh[ks] = *(const shortx8*)(qph + ks * 32 + quad * 8);
            ql[ks] = *(const shortx8*)(qpl + ks * 32 + quad * 8);
        }
    }

    floatx4 s[32];
    #pragma unroll
    for (int i = 0; i < 32; ++i) s[i] = (floatx4){0.f, 0.f, 0.f, 0.f};

    // ---- Phase 1: scoresT = K . Q^T, K fragments direct from global ----
    #pragma unroll
    for (int c = 0; c < 8; ++c) {
        if (c < nch) {
            #pragma unroll
            for (int kt = 0; kt < 4; ++kt) {
                size_t roff = (size_t)(bS + c * 64 + kt * 16 + l16) * DIM + h * 64;
                const u16* rh = Kh + roff;
                const u16* rl = Kl + roff;
                shortx8 kh0 = *(const shortx8*)(rh + quad * 8);
                shortx8 kh1 = *(const shortx8*)(rh + 32 + quad * 8);
                shortx8 kl0 = *(const shortx8*)(rl + quad * 8);
                shortx8 kl1 = *(const shortx8*)(rl + 32 + quad * 8);
                floatx4 a = s[c * 4 + kt];
                a = __builtin_amdgcn_mfma_f32_16x16x32_bf16(kh0, qh[0], a, 0, 0, 0);
                a = __builtin_amdgcn_mfma_f32_16x16x32_bf16(kh1, qh[1], a, 0, 0, 0);
                a = __builtin_amdgcn_mfma_f32_16x16x32_bf16(kh0, ql[0], a, 0, 0, 0);
                a = __builtin_amdgcn_mfma_f32_16x16x32_bf16(kh1, ql[1], a, 0, 0, 0);
                a = __builtin_amdgcn_mfma_f32_16x16x32_bf16(kl0, qh[0], a, 0, 0, 0);
                a = __builtin_amdgcn_mfma_f32_16x16x32_bf16(kl1, qh[1], a, 0, 0, 0);
                s[c * 4 + kt] = a;
            }
        }
    }

    // ---- Phase 2: softmax -> cumsum decay -> second softmax (registers) ----
    float m1 = -1e30f;
    #pragma unroll
    for (int kt = 0; kt < 32; ++kt) {
        if (kt < nkt) {
            #pragma unroll
            for (int r = 0; r < 4; ++r) {
                int key = kt * 16 + quad * 4 + r;
                float sv = (key <= kmax) ? s[kt][r] * 0.125f : -1e30f;
                s[kt][r] = sv;
                m1 = fmaxf(m1, sv);
            }
        }
    }
    m1 = fmaxf(m1, __shfl_xor(m1, 16, 64));
    m1 = fmaxf(m1, __shfl_xor(m1, 32, 64));

    float sum1 = 0.f;
    #pragma unroll
    for (int kt = 0; kt < 32; ++kt) {
        if (kt < nkt) {
            #pragma unroll
            for (int r = 0; r < 4; ++r) sum1 += __expf(s[kt][r] - m1);
        }
    }
    sum1 += __shfl_xor(sum1, 16, 64);
    sum1 += __shfl_xor(sum1, 32, 64);
    float inv1 = 1.f / sum1;

    float carry = 0.f, m2 = -1e30f;
    #pragma unroll
    for (int kt = 0; kt < 32; ++kt) {
        if (kt < nkt) {
            float e0 = __expf(s[kt][0] - m1);
            float e1 = __expf(s[kt][1] - m1);
            float e2 = __expf(s[kt][2] - m1);
            float e3 = __expf(s[kt][3] - m1);
            float c0 = e0, c1 = c0 + e1, c2 = c1 + e2, c3 = c2 + e3;
            float q0 = __shfl(c3, l16, 64);
            float q1 = __shfl(c3, l16 + 16, 64);
            float q2 = __shfl(c3, l16 + 32, 64);
            float q3 = __shfl(c3, l16 + 48, 64);
            float excl = carry;
            if (quad > 0) excl += q0;
            if (quad > 1) excl += q1;
            if (quad > 2) excl += q2;
            carry += q0 + q1 + q2 + q3;
            float cc[4] = {c0, c1, c2, c3};
            #pragma unroll
            for (int r = 0; r < 4; ++r) {
                int key = kt * 16 + quad * 4 + r;
                float distcum = (excl + cc[r]) * inv1;
                float rem = fmaxf(1.f - distcum, 0.f);
                float prod = fmaxf(rem * (float)(qrow - key), 0.f);
                float te = fmaxf(__expf(sqrtf(prod) * gamma), 1e-5f);
                te = fminf(te, 1e5f);
                float sv2 = s[kt][r] * te;
                s[kt][r] = sv2;
                m2 = fmaxf(m2, sv2);
            }
        }
    }
    m2 = fmaxf(m2, __shfl_xor(m2, 16, 64));
    m2 = fmaxf(m2, __shfl_xor(m2, 32, 64));

    float sum2 = 0.f;
    #pragma unroll
    for (int kt = 0; kt < 32; ++kt) {
        if (kt < nkt) {
            #pragma unroll
            for (int r = 0; r < 4; ++r) {
                float p = __expf(s[kt][r] - m2);
                s[kt][r] = p;
                sum2 += p;
            }
        }
    }
    sum2 += __shfl_xor(sum2, 16, 64);
    sum2 += __shfl_xor(sum2, 32, 64);
    float inv2 = 1.f / sum2;

    // ---- Phase 3: O = P . V, Vt fragments direct from global ----
    floatx4 o[4];
    #pragma unroll
    for (int i = 0; i < 4; ++i) o[i] = (floatx4){0.f, 0.f, 0.f, 0.f};

    #pragma unroll
    for (int c = 0; c < 8; ++c) {
        if (c < nch) {
            // repack this chunk of P into A-fragment layout (per-wave LDS, no barrier)
            #pragma unroll
            for (int kt = 0; kt < 4; ++kt) {
                floatx4 pv = s[c * 4 + kt];
                u16 hh[4], ll[4];
                #pragma unroll
                for (int r = 0; r < 4; ++r) bfsplit(pv[r] * inv2, hh[r], ll[r]);
                uint2 hw, lw;
                hw.x = (unsigned)hh[0] | ((unsigned)hh[1] << 16);
                hw.y = (unsigned)hh[2] | ((unsigned)hh[3] << 16);
                lw.x = (unsigned)ll[0] | ((unsigned)ll[1] << 16);
                lw.y = (unsigned)ll[2] | ((unsigned)ll[3] << 16);
                *(uint2*)&PB[w][0][l16][kt * 16 + quad * 4] = hw;
                *(uint2*)&PB[w][1][l16][kt * 16 + quad * 4] = lw;
            }
            shortx8 ph0 = *(const shortx8*)&PB[w][0][l16][quad * 8];
            shortx8 ph1 = *(const shortx8*)&PB[w][0][l16][32 + quad * 8];
            shortx8 pl0 = *(const shortx8*)&PB[w][1][l16][quad * 8];
            shortx8 pl1 = *(const shortx8*)&PB[w][1][l16][32 + quad * 8];
            #pragma unroll
            for (int dt = 0; dt < 4; ++dt) {
                size_t roff = ((size_t)bh * 64 + dt * 16 + l16) * SEQ + c * 64;
                const u16* rh = Vth + roff;
                const u16* rl = Vtl + roff;
                shortx8 vh0 = *(const shortx8*)(rh + quad * 8);
                shortx8 vh1 = *(const shortx8*)(rh + 32 + quad * 8);
                shortx8 vl0 = *(const shortx8*)(rl + quad * 8);
                shortx8 vl1 = *(const shortx8*)(rl + 32 + quad * 8);
                floatx4 a = o[dt];
                a = __builtin_amdgcn_mfma_f32_16x16x32_bf16(ph0, vh0, a, 0, 0, 0);
                a = __builtin_amdgcn_mfma_f32_16x16x32_bf16(ph1, vh1, a, 0, 0, 0);
                a = __builtin_amdgcn_mfma_f32_16x16x32_bf16(ph0, vl0, a, 0, 0, 0);
                a = __builtin_amdgcn_mfma_f32_16x16x32_bf16(ph1, vl1, a, 0, 0, 0);
                a = __builtin_amdgcn_mfma_f32_16x16x32_bf16(pl0, vh0, a, 0, 0, 0);
                a = __builtin_amdgcn_mfma_f32_16x16x32_bf16(pl1, vh1, a, 0, 0, 0);
                o[dt] = a;
            }
        }
    }

    #pragma unroll
    for (int dt = 0; dt < 4; ++dt) {
        #pragma unroll
        for (int r = 0; r < 4; ++r) {
            int row = qrow0 + quad * 4 + r;
            float v = o[dt][r];
            if (m0 && row == 0) v = 0.f;
            u16 hh, ll; bfsplit(v, hh, ll);
            size_t oo = (size_t)(bS + row) * DIM + h * 64 + dt * 16 + l16;
            AOh[oo] = hh; AOl[oo] = ll;
        }
    }
}

static GD mkgd(const u16* Ah, const u16* Al, const u16* Bh, const u16* Bl,
               int K, int Bstride, int Boff, const float* bias, const float* bias2,
               int N, int mode, float* Cf, u16* Ch, u16* Cl, u16* Ch2, u16* Cl2) {
    GD d; d.Ah = Ah; d.Al = Al; d.Bh = Bh; d.Bl = Bl; d.bias = bias; d.bias2 = bias2;
    d.Cf = Cf; d.Ch = Ch; d.Cl = Cl; d.Ch2 = Ch2; d.Cl2 = Cl2;
    d.K = K; d.Bstride = Bstride; d.Boff = Boff; d.N = N; d.mode = mode;
    return d;
}
static void run_gemm1(const GD& d, hipStream_t stream) {
    dim3 g(((d.N + 63) & ~63) / 64, TOK / 128, 1);
    gemm_pp<<<g, dim3(256), 0, stream>>>(d, d);
}
static void run_gemm2(const GD& d0, const GD& d1, hipStream_t stream) {
    int n0 = (d0.N + 63) & ~63, n1 = (d1.N + 63) & ~63;
    dim3 g(((n0 > n1 ? n0 : n1)) / 64, TOK / 128, 2);
    gemm_pp<<<g, dim3(256), 0, stream>>>(d0, d1);
}

extern "C" void kernel_launch(void* const* d_in, const int* in_sizes, int n_in,
                              void* d_out, int out_size, void* d_ws, size_t ws_size,
                              hipStream_t stream) {
    (void)in_sizes; (void)n_in;
    const int* c_data    = (const int*)d_in[0];
    const int* ca_data   = (const int*)d_in[1];
    const float* c_emb   = (const float*)d_in[2];
    const float* ca_emb  = (const float*)d_in[3];
    const float* Wk  = (const float*)d_in[4];
    const float* bk  = (const float*)d_in[5];
    const float* Wv  = (const float*)d_in[6];
    const float* bv  = (const float*)d_in[7];
    const float* Wo  = (const float*)d_in[8];
    const float* bo  = (const float*)d_in[9];
    const float* gammas = (const float*)d_in[10];
    const float* ln1s = (const float*)d_in[11];
    const float* ln1b = (const float*)d_in[12];
    const float* W1  = (const float*)d_in[13];
    const float* b1  = (const float*)d_in[14];
    const float* W2  = (const float*)d_in[15];
    const float* b2  = (const float*)d_in[16];
    const float* ln2s = (const float*)d_in[17];
    const float* ln2b = (const float*)d_in[18];
    const float* oW0 = (const float*)d_in[19];
    const float* ob0 = (const float*)d_in[20];
    const float* oW1 = (const float*)d_in[21];
    const float* ob1 = (const float*)d_in[22];
    const float* oW2 = (const float*)d_in[23];
    const float* ob2 = (const float*)d_in[24];

    float* out = (float*)d_out;
    const size_t MB = 1024 * 1024;
    if (ws_size < 64 * MB) {
        VAKT_52226802319686_kernel<<<dim3((out_size + 255) / 256), dim3(256), 0, stream>>>(out, out_size);
        return;
    }
    char* wsp = (char*)d_ws;
    // persistent activation planes
    u16* x0ph = (u16*)(wsp);            u16* x0pl = (u16*)(wsp + 4 * MB);
    u16* yph  = (u16*)(wsp + 8 * MB);   u16* ypl  = (u16*)(wsp + 12 * MB);
    u16* xph  = (u16*)(wsp + 16 * MB);  u16* xpl  = (u16*)(wsp + 20 * MB);
    // per-layer weight planes [24,35)
    u16* btQVh = (u16*)(wsp + 24 * MB); u16* btQVl = (u16*)(wsp + 25 * MB);
    u16* btWoh = (u16*)(wsp + 26 * MB); u16* btWol = (u16*)(wsp + 26 * MB + 512 * 1024);
    u16* btW1h = (u16*)(wsp + 27 * MB); u16* btW1l = (u16*)(wsp + 29 * MB);
    u16* btW2h = (u16*)(wsp + 31 * MB); u16* btW2l = (u16*)(wsp + 33 * MB);
    // per-layer activation scratch
    u16* qphh = (u16*)(wsp + 35 * MB);  u16* qpll = (u16*)(wsp + 39 * MB);
    u16* vphh = (u16*)(wsp + 43 * MB);  u16* vpll = (u16*)(wsp + 47 * MB);
    u16* Vth  = (u16*)(wsp + 51 * MB);  u16* Vtl  = (u16*)(wsp + 55 * MB);
    u16* kphh = xph;                    u16* kpll = xpl;   // li 0,1 only (xp not live yet)
    float* t1 = (float*)(wsp + 35 * MB);                   // qp region, after attn
    u16* ffh  = (u16*)(wsp + 43 * MB);  u16* ffl  = (u16*)(wsp + 51 * MB);  // vp+Vt, after Wo
    // head
    u16* hch = (u16*)(wsp + 24 * MB);   u16* hcl = (u16*)(wsp + 32 * MB);
    u16* bH0h = (u16*)(wsp + 40 * MB);  u16* bH0l = (u16*)(wsp + 41 * MB);
    u16* bH1h = (u16*)(wsp + 42 * MB);  u16* bH1l = (u16*)(wsp + 43 * MB);
    u16* bH2h = (u16*)(wsp + 44 * MB);  u16* bH2l = (u16*)(wsp + 46 * MB);
    u16* h1ph = (u16*)(wsp + 48 * MB);  u16* h1pl = (u16*)(wsp + 52 * MB);
    u16* h2ph = (u16*)(wsp + 24 * MB);  u16* h2pl = (u16*)(wsp + 32 * MB);

    embed_pl<<<dim3(TOK), dim3(256), 0, stream>>>(c_data, ca_data, c_emb, ca_emb,
                                                  x0ph, x0pl, yph, ypl);

    for (int li = 0; li < 6; ++li) {
        int pos = (li != 2 && li != 4);
        int m0 = (li == 3 || li == 5);

        wsplit_layer<<<dim3(pos ? 704 : 192), dim3(256), 0, stream>>>(
            Wk + (size_t)li * DIM * DIM, Wv + (size_t)li * DIM * DIM,
            Wo + (size_t)li * DIM * DIM,
            W1 + (size_t)li * DIM * FFD, W2 + (size_t)li * FFD * DIM,
            btQVh, btQVl, btWoh, btWol, btW1h, btW1l, btW2h, btW2l);

        const u16 *Kph, *Kpl;
        const u16 *residH, *residL; u16 *outH, *outL;
        if (li == 0 || li == 1) {
            // qv fused (A=y) + k (A=x0) in one dual-slot launch
            GD dqv = mkgd(yph, ypl, btQVh, btQVl, DIM, DIM, 0,
                          bk + li * DIM, bv + li * DIM, 1024, EP_PL | EP_QV,
                          nullptr, qphh, qpll, vphh, vpll);
            GD dk = mkgd(x0ph, x0pl, btQVh, btQVl, DIM, DIM, 0,
                         bk + li * DIM, nullptr, DIM, EP_PL,
                         nullptr, kphh, kpll, nullptr, nullptr);
            run_gemm2(dqv, dk, stream);
            Kph = kphh; Kpl = kpll;
            residH = yph; residL = ypl; outH = yph; outL = ypl;
        } else if (li == 2 || li == 4) {
            const u16* ah = (li == 2) ? x0ph : xph;
            const u16* al = (li == 2) ? x0pl : xpl;
            GD dqv = mkgd(ah, al, btQVh, btQVl, DIM, DIM, 0,
                          bk + li * DIM, bv + li * DIM, 1024, EP_PL | EP_QV,
                          nullptr, qphh, qpll, vphh, vpll);
            run_gemm1(dqv, stream);
            Kph = qphh; Kpl = qpll;
            residH = (li == 2) ? x0ph : xph; residL = (li == 2) ? x0pl : xpl;
            outH = xph; outL = xpl;
        } else {
            // q (A=x) + v (A=y) dual-slot
            GD dq = mkgd(xph, xpl, btQVh, btQVl, DIM, DIM, 0,
                         bk + li * DIM, nullptr, DIM, EP_PL,
                         nullptr, qphh, qpll, nullptr, nullptr);
            GD dv = mkgd(yph, ypl, btQVh + 512 * 512, btQVl + 512 * 512, DIM, DIM, 0,
                         bv + li * DIM, nullptr, DIM, EP_PL,
                         nullptr, vphh, vpll, nullptr, nullptr);
            run_gemm2(dq, dv, stream);
            Kph = qphh; Kpl = qpll;
            residH = xph; residL = xpl; outH = xph; outL = xpl;
        }

        vtsplit_pp<<<dim3(SEQ / 64, BATCH * NHEAD), dim3(256), 0, stream>>>(vphh, vpll, Vth, Vtl);
        attn_mf<<<dim3(8, NHEAD, BATCH), dim3(256), 0, stream>>>(
            qphh, qpll, Kph, Kpl, Vth, Vtl, gammas + li * NHEAD, vphh, vpll, m0);

        GD dwo = mkgd(vphh, vpll, btWoh, btWol, DIM, DIM, 0,
                      bo + li * DIM, nullptr, DIM, EP_F32,
                      t1, nullptr, nullptr, nullptr, nullptr);
        run_gemm1(dwo, stream);
        add_ln_pl<<<dim3(TOK / 4), dim3(256), 0, stream>>>(residH, residL, t1,
                                                           ln1s + li * DIM, ln1b + li * DIM,
                                                           outH, outL);
        if (pos) {
            for (int c = 0; c < 2; ++c) {
                GD d1c = mkgd(outH, outL,
                              btW1h + (size_t)c * 1024 * DIM, btW1l + (size_t)c * 1024 * DIM,
                              DIM, DIM, 0, b1 + li * FFD + c * 1024, nullptr,
                              1024, EP_RELU | EP_PL, nullptr, ffh, ffl, nullptr, nullptr);
                run_gemm1(d1c, stream);
                GD d2c = mkgd(ffh, ffl, btW2h, btW2l, 1024, FFD, c * 1024,
                              b2 + li * DIM, nullptr, DIM,
                              (c == 0) ? EP_F32 : (EP_F32 | EP_ACC),
                              t1, nullptr, nullptr, nullptr, nullptr);
                run_gemm1(d2c, stream);
            }
            add_ln_pl<<<dim3(TOK / 4), dim3(256), 0, stream>>>(outH, outL, t1,
                                                               ln2s + li * DIM, ln2b + li * DIM,
                                                               outH, outL);
        }
    }

    concat_pl<<<dim3(TOK), dim3(256), 0, stream>>>(xph, xpl, x0ph, x0pl, hch, hcl);
    wsplit_head<<<dim3(512), dim3(256), 0, stream>>>(oW0, oW1, oW2,
                                                     bH0h, bH0l, bH1h, bH1l, bH2h, bH2l);
    GD g0 = mkgd(hch, hcl, bH0h, bH0l, 1024, 1024, 0, ob0, nullptr, 512,
                 EP_RELU | EP_PL, nullptr, h1ph, h1pl, nullptr, nullptr);
    run_gemm1(g0, stream);
    GD g1 = mkgd(h1ph, h1pl, bH1h, bH1l, 512, 512, 0, ob1, nullptr, 1024,
                 EP_RELU | EP_PL, nullptr, h2ph, h2pl, nullptr, nullptr);
    run_gemm1(g1, stream);
    GD g2 = mkgd(h2ph, h2pl, bH2h, bH2l, 1024, 1024, 0, ob2, nullptr, 1000,
                 EP_F32, out, nullptr, nullptr, nullptr, nullptr);
    run_gemm1(g2, stream);
}

// Round 5
// 1422.215 us; speedup vs baseline: 1.2117x; 1.2117x over previous
//
#include <hip/hip_runtime.h>

#define TOK 4096
#define SEQ 512
#define BATCH 8
#define DIM 512
#define NHEAD 8
#define DK 64
#define FFD 2048

typedef unsigned short u16;
typedef unsigned int u32;
typedef float floatx4 __attribute__((ext_vector_type(4)));
typedef short shortx8 __attribute__((ext_vector_type(8)));

// epilogue mode bits
#define EP_RELU 1
#define EP_ACC  2
#define EP_F32  4
#define EP_PL   8
#define EP_QV  16

__device__ __forceinline__ u16 bfh(float f) {
    union { float f; unsigned u; } x; x.f = f;
    return (u16)((x.u + 0x7fffu + ((x.u >> 16) & 1u)) >> 16);
}
__device__ __forceinline__ float bff(u16 h) {
    union { unsigned u; float f; } x; x.u = (unsigned)h << 16; return x.f;
}
// truncation-based hi/lo split: residual ~2^-16 relative
__device__ __forceinline__ void bfsplit(float v, u16& h, u16& l) {
    union { float f; unsigned u; } x; x.f = v;
    union { unsigned u; float f; } hb; hb.u = x.u & 0xffff0000u;
    float rem = v - hb.f;
    union { float f; unsigned u; } rr; rr.f = rem;
    h = (u16)(x.u >> 16);
    l = (u16)(rr.u >> 16);
}
__device__ __forceinline__ float rec2(u16 h, u16 l) { return bff(h) + bff(l); }
__device__ __forceinline__ float wave_sum(float v) {
    #pragma unroll
    for (int off = 32; off; off >>= 1) v += __shfl_xor(v, off, 64);
    return v;
}

#define GLDS16(gp, lp) __builtin_amdgcn_global_load_lds( \
    (const __attribute__((address_space(1))) u32*)(const void*)(gp), \
    (__attribute__((address_space(3))) u32*)(void*)(lp), 16, 0, 0)

// sentinel: ws too small
__global__ void VAKT_52226802319686_kernel(float* out, int n) {
    int i = blockIdx.x * 256 + threadIdx.x;
    if (i < n) out[i] = 524288.f;
}

__global__ void embed_pl(const int* cd, const int* cad, const float* cemb,
                         const float* caemb,
                         u16* x0h, u16* x0l, u16* yh, u16* yl) {
    int tok = blockIdx.x;
    int idx = cd[tok];
    int resp = (cad[tok] - idx) / 1000;
    for (int d = threadIdx.x; d < DIM; d += 256) {
        float e = cemb[(size_t)idx * DIM + d];
        float yv = e + caemb[resp * DIM + d];
        size_t o = (size_t)tok * DIM + d;
        u16 hh, ll;
        bfsplit(e, hh, ll);  x0h[o] = hh; x0l[o] = ll;
        bfsplit(yv, hh, ll); yh[o] = hh;  yl[o] = ll;
    }
}

__global__ void concat_pl(const u16* Xh, const u16* Xl, const u16* X0h, const u16* X0l,
                          u16* Hh, u16* Hl) {
    int tok = blockIdx.x;
    for (int d = threadIdx.x; d < 2 * DIM; d += 256) {
        size_t s = (size_t)tok * DIM + ((d < DIM) ? d : d - DIM);
        size_t o = (size_t)tok * (2 * DIM) + d;
        Hh[o] = (d < DIM) ? Xh[s] : X0h[s];
        Hl[o] = (d < DIM) ? Xl[s] : X0l[s];
    }
}

// resid from planes + f32 delta -> LN -> planes out (in-place safe per-row)
__global__ void add_ln_pl(const u16* Xh, const u16* Xl, const float* Dl,
                          const float* sc, const float* bi, u16* Oh, u16* Ol) {
    int lane = threadIdx.x & 63, w = threadIdx.x >> 6;
    size_t row = (size_t)blockIdx.x * 4 + w;
    const u16* xh = Xh + row * DIM;
    const u16* xl = Xl + row * DIM;
    const float* dr = Dl + row * DIM;
    float v[8]; float sum = 0.f, sq = 0.f;
    for (int i = 0; i < 8; i++) {
        int d = i * 64 + lane;
        float t = rec2(xh[d], xl[d]) + dr[d];
        v[i] = t; sum += t; sq += t * t;
    }
    sum = wave_sum(sum); sq = wave_sum(sq);
    float mean = sum * (1.0f / 512.0f);
    float var = sq * (1.0f / 512.0f) - mean * mean;
    float rstd = rsqrtf(var + 1e-5f);
    for (int i = 0; i < 8; i++) {
        int d = i * 64 + lane;
        float val = (v[i] - mean) * rstd * sc[d] + bi[d];
        u16 hh, ll; bfsplit(val, hh, ll);
        Oh[row * DIM + d] = hh; Ol[row * DIM + d] = ll;
    }
}

// one 64x64 transpose+split tile: W[K][N] fp32 -> dst [Npad][K] u16 hi/lo
__device__ __forceinline__ void wtile_body(float (*T)[65], const float* W, int K, int N,
                                           int k0, int n0, u16* dh, u16* dl) {
    int t = threadIdx.x;
    for (int i = 0; i < 16; i++) {
        int idx = i * 256 + t;
        int kr = idx >> 6, nc = idx & 63;
        int gn = n0 + nc;
        T[kr][nc] = (gn < N) ? W[(size_t)(k0 + kr) * N + gn] : 0.f;
    }
    __syncthreads();
    for (int i = 0; i < 16; i++) {
        int idx = i * 256 + t;
        int nr = idx >> 6, kc = idx & 63;
        float v = T[kc][nr];
        u16 h = bfh(v);
        float rem = v - bff(h);
        size_t o = (size_t)(n0 + nr) * K + k0 + kc;
        dh[o] = h; dl[o] = bfh(rem);
    }
}

// all weight splits for one layer in a single launch.
// grid 192 (Wk,Wv,Wo) or 704 (+W1,W2)
__global__ __launch_bounds__(256) void wsplit_layer(
    const float* Wk, const float* Wv, const float* Wo,
    const float* W1, const float* W2,
    u16* qvh, u16* qvl, u16* woh, u16* wol,
    u16* w1h, u16* w1l, u16* w2h, u16* w2l) {
    __shared__ float T[64][65];
    int bid = blockIdx.x;
    if (bid < 192) {
        int m = bid >> 6, t2 = bid & 63;
        int k0 = (t2 & 7) * 64, n0 = (t2 >> 3) * 64;
        const float* W = (m == 0) ? Wk : (m == 1) ? Wv : Wo;
        u16* dh = (m == 0) ? qvh : (m == 1) ? (qvh + 512 * 512) : woh;
        u16* dl = (m == 0) ? qvl : (m == 1) ? (qvl + 512 * 512) : wol;
        wtile_body(T, W, 512, 512, k0, n0, dh, dl);
    } else if (bid < 448) {
        int t2 = bid - 192;
        wtile_body(T, W1, 512, 2048, (t2 & 7) * 64, (t2 >> 3) * 64, w1h, w1l);
    } else {
        int t2 = bid - 448;
        wtile_body(T, W2, 2048, 512, (t2 & 31) * 64, (t2 >> 5) * 64, w2h, w2l);
    }
}

// head weight splits: oW0 (1024x512), oW1 (512x1024), oW2 (1024x1000->pad1024). grid 512
__global__ __launch_bounds__(256) void wsplit_head(
    const float* oW0, const float* oW1, const float* oW2,
    u16* h0h, u16* h0l, u16* h1h, u16* h1l, u16* h2h, u16* h2l) {
    __shared__ float T[64][65];
    int bid = blockIdx.x;
    if (bid < 128) {
        wtile_body(T, oW0, 1024, 512, (bid & 15) * 64, (bid >> 4) * 64, h0h, h0l);
    } else if (bid < 256) {
        int t2 = bid - 128;
        wtile_body(T, oW1, 512, 1024, (t2 & 7) * 64, (t2 >> 3) * 64, h1h, h1l);
    } else {
        int t2 = bid - 256;
        wtile_body(T, oW2, 1024, 1000, (t2 & 15) * 64, (t2 >> 4) * 64, h2h, h2l);
    }
}

struct GD {
    const u16 *Ah, *Al, *Bh, *Bl;
    const float *bias, *bias2;
    float* Cf; u16 *Ch, *Cl, *Ch2, *Cl2;
    int K, Bstride, Boff, N, mode;
};

// C[4096,N] = A @ Bt^T (+bias). dual problem slots via blockIdx.z.
__global__ __launch_bounds__(256) void gemm_pp(GD d0, GD d1) {
    const GD d = blockIdx.z ? d1 : d0;
    const int bn0 = blockIdx.x * 64;
    if (bn0 >= ((d.N + 63) & ~63)) return;
    __shared__ u16 sm[24576];
    const int t = threadIdx.x;
    const int lane = t & 63, w = t >> 6;
    const int l16 = lane & 15, quad = lane >> 4;
    const int bm0 = blockIdx.y * 128;
    const int wm = (w & 1) * 64, wn = (w >> 1) * 32;

    floatx4 acc[4][2];
    #pragma unroll
    for (int mi = 0; mi < 4; mi++)
        #pragma unroll
        for (int ni = 0; ni < 2; ni++) acc[mi][ni] = (floatx4){0.f, 0.f, 0.f, 0.f};

    for (int k0 = 0; k0 < d.K; k0 += 64) {
        __syncthreads();
        #pragma unroll
        for (int p = 0; p < 2; ++p) {
            const u16* Asrc = p ? d.Al : d.Ah;
            #pragma unroll
            for (int rr = 0; rr < 4; ++rr) {
                int idx = (rr * 4 + w) * 64 + lane;
                int row = idx >> 3;
                int sg = (idx & 7) ^ (row & 7);
                const u16* gp = Asrc + (size_t)(bm0 + row) * d.K + k0 + sg * 8;
                u16* lp = sm + p * 8192 + (rr * 4 + w) * 512;
                GLDS16(gp, lp);
            }
        }
        #pragma unroll
        for (int p = 0; p < 2; ++p) {
            const u16* Bsrc = p ? d.Bl : d.Bh;
            #pragma unroll
            for (int rr = 0; rr < 2; ++rr) {
                int idx = (rr * 4 + w) * 64 + lane;
                int row = idx >> 3;
                int sg = (idx & 7) ^ (row & 7);
                const u16* gp = Bsrc + (size_t)(bn0 + row) * d.Bstride + d.Boff + k0 + sg * 8;
                u16* lp = sm + 16384 + p * 4096 + (rr * 4 + w) * 512;
                GLDS16(gp, lp);
            }
        }
        __syncthreads();
        #pragma unroll
        for (int ks = 0; ks < 2; ++ks) {
            shortx8 ah[4], al[4], bh2[2], bl2[2];
            #pragma unroll
            for (int mi = 0; mi < 4; ++mi) {
                int row = wm + mi * 16 + l16;
                int s = (ks * 4 + quad) ^ (row & 7);
                ah[mi] = *(const shortx8*)&sm[row * 64 + s * 8];
                al[mi] = *(const shortx8*)&sm[8192 + row * 64 + s * 8];
            }
            #pragma unroll
            for (int ni = 0; ni < 2; ++ni) {
                int row = wn + ni * 16 + l16;
                int s = (ks * 4 + quad) ^ (row & 7);
                bh2[ni] = *(const shortx8*)&sm[16384 + row * 64 + s * 8];
                bl2[ni] = *(const shortx8*)&sm[20480 + row * 64 + s * 8];
            }
            #pragma unroll
            for (int mi = 0; mi < 4; ++mi)
                #pragma unroll
                for (int ni = 0; ni < 2; ++ni) {
                    acc[mi][ni] = __builtin_amdgcn_mfma_f32_16x16x32_bf16(ah[mi], bh2[ni], acc[mi][ni], 0, 0, 0);
                    acc[mi][ni] = __builtin_amdgcn_mfma_f32_16x16x32_bf16(ah[mi], bl2[ni], acc[mi][ni], 0, 0, 0);
                    acc[mi][ni] = __builtin_amdgcn_mfma_f32_16x16x32_bf16(al[mi], bh2[ni], acc[mi][ni], 0, 0, 0);
                }
        }
    }
    #pragma unroll
    for (int ni = 0; ni < 2; ++ni) {
        int col = bn0 + wn + ni * 16 + l16;
        if (col < d.N) {
            float bv;
            if (d.mode & EP_ACC) bv = 0.f;
            else if ((d.mode & EP_QV) && col >= 512) bv = d.bias2[col - 512];
            else bv = d.bias[col];
            #pragma unroll
            for (int mi = 0; mi < 4; ++mi) {
                #pragma unroll
                for (int r = 0; r < 4; ++r) {
                    int row = bm0 + wm + mi * 16 + quad * 4 + r;
                    float v = acc[mi][ni][r] + bv;
                    if ((d.mode & EP_RELU) && v < 0.f) v = 0.f;
                    if (d.mode & EP_ACC) v += d.Cf[(size_t)row * d.N + col];
                    if (d.mode & EP_F32) d.Cf[(size_t)row * d.N + col] = v;
                    if (d.mode & EP_PL) {
                        u16 hh, ll; bfsplit(v, hh, ll);
                        if ((d.mode & EP_QV) && col >= 512) {
                            size_t o = (size_t)row * 512 + col - 512;
                            d.Ch2[o] = hh; d.Cl2[o] = ll;
                        } else {
                            size_t o = (size_t)row * ((d.mode & EP_QV) ? 512 : d.N) + col;
                            d.Ch[o] = hh; d.Cl[o] = ll;
                        }
                    }
                }
            }
        }
    }
}

// per-head transpose of pre-split V planes: vh/vl [4096][512] -> Vt[bh][64 d][512 s]
__global__ __launch_bounds__(256) void vtsplit_pp(const u16* __restrict__ vh,
                                                  const u16* __restrict__ vl,
                                                  u16* __restrict__ dh, u16* __restrict__ dl) {
    __shared__ u16 Th[64][72], Tl[64][72];
    const int t = threadIdx.x;
    const int s0 = blockIdx.x * 64;
    const int bh = blockIdx.y;
    const int b = bh >> 3, h = bh & 7;
    #pragma unroll
    for (int j = 0; j < 2; ++j) {
        int idx = j * 256 + t;
        int r = idx >> 3, sg = idx & 7;
        size_t src = (size_t)(b * SEQ + s0 + r) * DIM + h * 64 + sg * 8;
        *(uint4*)&Th[r][sg * 8] = *(const uint4*)(vh + src);
        *(uint4*)&Tl[r][sg * 8] = *(const uint4*)(vl + src);
    }
    __syncthreads();
    #pragma unroll
    for (int j = 0; j < 2; ++j) {
        int idx = j * 256 + t;
        int d = idx >> 3, sg = idx & 7;
        union { u16 e[8]; uint4 q; } xh, xl;
        #pragma unroll
        for (int k = 0; k < 8; ++k) { xh.e[k] = Th[sg * 8 + k][d]; xl.e[k] = Tl[sg * 8 + k][d]; }
        size_t dst = ((size_t)bh * 64 + d) * SEQ + s0 + sg * 8;
        *(uint4*)(dh + dst) = xh.q;
        *(uint4*)(dl + dst) = xl.q;
    }
}

// MFMA attention. One block = 64 q-rows of one (b,h), 4 waves x 16 rows.
// K/V staged chunk-wise into LDS via global_load_lds (linear dest, source-side
// XOR swizzle; reads use the same swizzle) -- same proven idiom as gemm_pp.
// Softmax / cumsum decay fully register-resident via swapped QK^T.
__global__ __launch_bounds__(256, 2) void attn_mf(
    const u16* __restrict__ Qh, const u16* __restrict__ Ql,
    const u16* __restrict__ Kh, const u16* __restrict__ Kl,
    const u16* __restrict__ Vth, const u16* __restrict__ Vtl,
    const float* __restrict__ gam, u16* __restrict__ AOh, u16* __restrict__ AOl,
    int m0) {
    __shared__ __align__(16) u16 KV[8192];            // [2 planes][64 rows][64] linear
    __shared__ __align__(16) u16 PB[4][2][16][72];    // per-wave P repack
    const int t = threadIdx.x;
    const int lane = t & 63, w = t >> 6;
    const int l16 = lane & 15, quad = lane >> 4;
    const int chunk = 7 - (int)blockIdx.x;            // heavy blocks dispatch first
    const int h = blockIdx.y, b = blockIdx.z;
    const int bS = b * SEQ;
    const int bh = b * NHEAD + h;
    const int nch = chunk + 1, nkt = nch * 4;
    const int qrow0 = chunk * 64 + w * 16;
    const int qrow = qrow0 + l16;
    const int kmax = qrow - m0;
    // staging geometry: seg-index = (rr*4+w)*64 + lane; row = idx>>3, sg swizzled
    const int strow = ((0 * 4 + w) * 64 + lane) >> 3; // recomputed per round below

    float g = gam[h];
    float gamma = -((g > 20.f) ? g : log1pf(__expf(g)));

    shortx8 qh[2], ql[2];
    {
        const u16* qph = Qh + (size_t)(bS + qrow) * DIM + h * 64;
        const u16* qpl = Ql + (size_t)(bS + qrow) * DIM + h * 64;
        #pragma unroll
        for (int ks = 0; ks < 2; ++ks) {
            qh[ks] = *(const shortx8*)(qph + ks * 32 + quad * 8);
            ql[ks] = *(const shortx8*)(qpl + ks * 32 + quad * 8);
        }
    }

    floatx4 s[32];
    #pragma unroll
    for (int i = 0; i < 32; ++i) s[i] = (floatx4){0.f, 0.f, 0.f, 0.f};

    // ---- Phase 1: scoresT = K . Q^T over causal key chunks ----
    #pragma unroll
    for (int c = 0; c < 8; ++c) {
        if (c < nch) {
            __syncthreads();
            #pragma unroll
            for (int p = 0; p < 2; ++p) {
                const u16* src = p ? Kl : Kh;
                #pragma unroll
                for (int rr = 0; rr < 2; ++rr) {
                    int idx = (rr * 4 + w) * 64 + lane;   // 0..511
                    int row = idx >> 3;
                    int sg = (idx & 7) ^ (row & 7);
                    const u16* gp = src + (size_t)(bS + c * 64 + row) * DIM + h * 64 + sg * 8;
                    u16* lp = KV + p * 4096 + (rr * 4 + w) * 512;
                    GLDS16(gp, lp);
                }
            }
            __syncthreads();
            #pragma unroll
            for (int kt = 0; kt < 4; ++kt) {
                int row = kt * 16 + l16;
                int s0i = (quad ^ (row & 7)) * 8;
                int s1i = ((4 + quad) ^ (row & 7)) * 8;
                shortx8 kh0 = *(const shortx8*)&KV[row * 64 + s0i];
                shortx8 kh1 = *(const shortx8*)&KV[row * 64 + s1i];
                shortx8 kl0 = *(const shortx8*)&KV[4096 + row * 64 + s0i];
                shortx8 kl1 = *(const shortx8*)&KV[4096 + row * 64 + s1i];
                floatx4 a = s[c * 4 + kt];
                a = __builtin_amdgcn_mfma_f32_16x16x32_bf16(kh0, qh[0], a, 0, 0, 0);
                a = __builtin_amdgcn_mfma_f32_16x16x32_bf16(kh1, qh[1], a, 0, 0, 0);
                a = __builtin_amdgcn_mfma_f32_16x16x32_bf16(kh0, ql[0], a, 0, 0, 0);
                a = __builtin_amdgcn_mfma_f32_16x16x32_bf16(kh1, ql[1], a, 0, 0, 0);
                a = __builtin_amdgcn_mfma_f32_16x16x32_bf16(kl0, qh[0], a, 0, 0, 0);
                a = __builtin_amdgcn_mfma_f32_16x16x32_bf16(kl1, qh[1], a, 0, 0, 0);
                s[c * 4 + kt] = a;
            }
        }
    }

    // ---- Phase 2: softmax -> cumsum decay -> second softmax (registers) ----
    float m1 = -1e30f;
    #pragma unroll
    for (int kt = 0; kt < 32; ++kt) {
        if (kt < nkt) {
            #pragma unroll
            for (int r = 0; r < 4; ++r) {
                int key = kt * 16 + quad * 4 + r;
                float sv = (key <= kmax) ? s[kt][r] * 0.125f : -1e30f;
                s[kt][r] = sv;
                m1 = fmaxf(m1, sv);
            }
        }
    }
    m1 = fmaxf(m1, __shfl_xor(m1, 16, 64));
    m1 = fmaxf(m1, __shfl_xor(m1, 32, 64));

    float sum1 = 0.f;
    #pragma unroll
    for (int kt = 0; kt < 32; ++kt) {
        if (kt < nkt) {
            #pragma unroll
            for (int r = 0; r < 4; ++r) sum1 += __expf(s[kt][r] - m1);
        }
    }
    sum1 += __shfl_xor(sum1, 16, 64);
    sum1 += __shfl_xor(sum1, 32, 64);
    float inv1 = 1.f / sum1;

    float carry = 0.f, m2 = -1e30f;
    #pragma unroll
    for (int kt = 0; kt < 32; ++kt) {
        if (kt < nkt) {
            float e0 = __expf(s[kt][0] - m1);
            float e1 = __expf(s[kt][1] - m1);
            float e2 = __expf(s[kt][2] - m1);
            float e3 = __expf(s[kt][3] - m1);
            float c0 = e0, c1 = c0 + e1, c2 = c1 + e2, c3 = c2 + e3;
            float q0 = __shfl(c3, l16, 64);
            float q1 = __shfl(c3, l16 + 16, 64);
            float q2 = __shfl(c3, l16 + 32, 64);
            float q3 = __shfl(c3, l16 + 48, 64);
            float excl = carry;
            if (quad > 0) excl += q0;
            if (quad > 1) excl += q1;
            if (quad > 2) excl += q2;
            carry += q0 + q1 + q2 + q3;
            float cc[4] = {c0, c1, c2, c3};
            #pragma unroll
            for (int r = 0; r < 4; ++r) {
                int key = kt * 16 + quad * 4 + r;
                float distcum = (excl + cc[r]) * inv1;
                float rem = fmaxf(1.f - distcum, 0.f);
                float prod = fmaxf(rem * (float)(qrow - key), 0.f);
                float te = fmaxf(__expf(sqrtf(prod) * gamma), 1e-5f);
                te = fminf(te, 1e5f);
                float sv2 = s[kt][r] * te;
                s[kt][r] = sv2;
                m2 = fmaxf(m2, sv2);
            }
        }
    }
    m2 = fmaxf(m2, __shfl_xor(m2, 16, 64));
    m2 = fmaxf(m2, __shfl_xor(m2, 32, 64));

    float sum2 = 0.f;
    #pragma unroll
    for (int kt = 0; kt < 32; ++kt) {
        if (kt < nkt) {
            #pragma unroll
            for (int r = 0; r < 4; ++r) {
                float p = __expf(s[kt][r] - m2);
                s[kt][r] = p;
                sum2 += p;
            }
        }
    }
    sum2 += __shfl_xor(sum2, 16, 64);
    sum2 += __shfl_xor(sum2, 32, 64);
    float inv2 = 1.f / sum2;

    // ---- Phase 3: O = P . V over causal key chunks ----
    floatx4 o[4];
    #pragma unroll
    for (int i = 0; i < 4; ++i) o[i] = (floatx4){0.f, 0.f, 0.f, 0.f};

    #pragma unroll
    for (int c = 0; c < 8; ++c) {
        if (c < nch) {
            __syncthreads();
            // issue V staging (async); P repack below overlaps its latency
            #pragma unroll
            for (int p = 0; p < 2; ++p) {
                const u16* src = p ? Vtl : Vth;
                #pragma unroll
                for (int rr = 0; rr < 2; ++rr) {
                    int idx = (rr * 4 + w) * 64 + lane;
                    int row = idx >> 3;
                    int sg = (idx & 7) ^ (row & 7);
                    const u16* gp = src + ((size_t)bh * 64 + row) * SEQ + c * 64 + sg * 8;
                    u16* lp = KV + p * 4096 + (rr * 4 + w) * 512;
                    GLDS16(gp, lp);
                }
            }
            // repack this chunk of P into A-fragment layout (per-wave LDS)
            #pragma unroll
            for (int kt = 0; kt < 4; ++kt) {
                floatx4 pv = s[c * 4 + kt];
                u16 hh[4], ll[4];
                #pragma unroll
                for (int r = 0; r < 4; ++r) bfsplit(pv[r] * inv2, hh[r], ll[r]);
                uint2 hw, lw;
                hw.x = (unsigned)hh[0] | ((unsigned)hh[1] << 16);
                hw.y = (unsigned)hh[2] | ((unsigned)hh[3] << 16);
                lw.x = (unsigned)ll[0] | ((unsigned)ll[1] << 16);
                lw.y = (unsigned)ll[2] | ((unsigned)ll[3] << 16);
                *(uint2*)&PB[w][0][l16][kt * 16 + quad * 4] = hw;
                *(uint2*)&PB[w][1][l16][kt * 16 + quad * 4] = lw;
            }
            __syncthreads();
            shortx8 ph0 = *(const shortx8*)&PB[w][0][l16][quad * 8];
            shortx8 ph1 = *(const shortx8*)&PB[w][0][l16][32 + quad * 8];
            shortx8 pl0 = *(const shortx8*)&PB[w][1][l16][quad * 8];
            shortx8 pl1 = *(const shortx8*)&PB[w][1][l16][32 + quad * 8];
            #pragma unroll
            for (int dt = 0; dt < 4; ++dt) {
                int row = dt * 16 + l16;
                int s0i = (quad ^ (row & 7)) * 8;
                int s1i = ((4 + quad) ^ (row & 7)) * 8;
                shortx8 vh0 = *(const shortx8*)&KV[row * 64 + s0i];
                shortx8 vh1 = *(const shortx8*)&KV[row * 64 + s1i];
                shortx8 vl0 = *(const shortx8*)&KV[4096 + row * 64 + s0i];
                shortx8 vl1 = *(const shortx8*)&KV[4096 + row * 64 + s1i];
                floatx4 a = o[dt];
                a = __builtin_amdgcn_mfma_f32_16x16x32_bf16(ph0, vh0, a, 0, 0, 0);
                a = __builtin_amdgcn_mfma_f32_16x16x32_bf16(ph1, vh1, a, 0, 0, 0);
                a = __builtin_amdgcn_mfma_f32_16x16x32_bf16(ph0, vl0, a, 0, 0, 0);
                a = __builtin_amdgcn_mfma_f32_16x16x32_bf16(ph1, vl1, a, 0, 0, 0);
                a = __builtin_amdgcn_mfma_f32_16x16x32_bf16(pl0, vh0, a, 0, 0, 0);
                a = __builtin_amdgcn_mfma_f32_16x16x32_bf16(pl1, vh1, a, 0, 0, 0);
                o[dt] = a;
            }
        }
    }

    #pragma unroll
    for (int dt = 0; dt < 4; ++dt) {
        #pragma unroll
        for (int r = 0; r < 4; ++r) {
            int row = qrow0 + quad * 4 + r;
            float v = o[dt][r];
            if (m0 && row == 0) v = 0.f;
            u16 hh, ll; bfsplit(v, hh, ll);
            size_t oo = (size_t)(bS + row) * DIM + h * 64 + dt * 16 + l16;
            AOh[oo] = hh; AOl[oo] = ll;
        }
    }
}

static GD mkgd(const u16* Ah, const u16* Al, const u16* Bh, const u16* Bl,
               int K, int Bstride, int Boff, const float* bias, const float* bias2,
               int N, int mode, float* Cf, u16* Ch, u16* Cl, u16* Ch2, u16* Cl2) {
    GD d; d.Ah = Ah; d.Al = Al; d.Bh = Bh; d.Bl = Bl; d.bias = bias; d.bias2 = bias2;
    d.Cf = Cf; d.Ch = Ch; d.Cl = Cl; d.Ch2 = Ch2; d.Cl2 = Cl2;
    d.K = K; d.Bstride = Bstride; d.Boff = Boff; d.N = N; d.mode = mode;
    return d;
}
static void run_gemm1(const GD& d, hipStream_t stream) {
    dim3 g(((d.N + 63) & ~63) / 64, TOK / 128, 1);
    gemm_pp<<<g, dim3(256), 0, stream>>>(d, d);
}
static void run_gemm2(const GD& d0, const GD& d1, hipStream_t stream) {
    int n0 = (d0.N + 63) & ~63, n1 = (d1.N + 63) & ~63;
    dim3 g(((n0 > n1 ? n0 : n1)) / 64, TOK / 128, 2);
    gemm_pp<<<g, dim3(256), 0, stream>>>(d0, d1);
}

extern "C" void kernel_launch(void* const* d_in, const int* in_sizes, int n_in,
                              void* d_out, int out_size, void* d_ws, size_t ws_size,
                              hipStream_t stream) {
    (void)in_sizes; (void)n_in;
    const int* c_data    = (const int*)d_in[0];
    const int* ca_data   = (const int*)d_in[1];
    const float* c_emb   = (const float*)d_in[2];
    const float* ca_emb  = (const float*)d_in[3];
    const float* Wk  = (const float*)d_in[4];
    const float* bk  = (const float*)d_in[5];
    const float* Wv  = (const float*)d_in[6];
    const float* bv  = (const float*)d_in[7];
    const float* Wo  = (const float*)d_in[8];
    const float* bo  = (const float*)d_in[9];
    const float* gammas = (const float*)d_in[10];
    const float* ln1s = (const float*)d_in[11];
    const float* ln1b = (const float*)d_in[12];
    const float* W1  = (const float*)d_in[13];
    const float* b1  = (const float*)d_in[14];
    const float* W2  = (const float*)d_in[15];
    const float* b2  = (const float*)d_in[16];
    const float* ln2s = (const float*)d_in[17];
    const float* ln2b = (const float*)d_in[18];
    const float* oW0 = (const float*)d_in[19];
    const float* ob0 = (const float*)d_in[20];
    const float* oW1 = (const float*)d_in[21];
    const float* ob1 = (const float*)d_in[22];
    const float* oW2 = (const float*)d_in[23];
    const float* ob2 = (const float*)d_in[24];

    float* out = (float*)d_out;
    const size_t MB = 1024 * 1024;
    if (ws_size < 64 * MB) {
        VAKT_52226802319686_kernel<<<dim3((out_size + 255) / 256), dim3(256), 0, stream>>>(out, out_size);
        return;
    }
    char* wsp = (char*)d_ws;
    // persistent activation planes
    u16* x0ph = (u16*)(wsp);            u16* x0pl = (u16*)(wsp + 4 * MB);
    u16* yph  = (u16*)(wsp + 8 * MB);   u16* ypl  = (u16*)(wsp + 12 * MB);
    u16* xph  = (u16*)(wsp + 16 * MB);  u16* xpl  = (u16*)(wsp + 20 * MB);
    // per-layer weight planes [24,35)
    u16* btQVh = (u16*)(wsp + 24 * MB); u16* btQVl = (u16*)(wsp + 25 * MB);
    u16* btWoh = (u16*)(wsp + 26 * MB); u16* btWol = (u16*)(wsp + 26 * MB + 512 * 1024);
    u16* btW1h = (u16*)(wsp + 27 * MB); u16* btW1l = (u16*)(wsp + 29 * MB);
    u16* btW2h = (u16*)(wsp + 31 * MB); u16* btW2l = (u16*)(wsp + 33 * MB);
    // per-layer activation scratch
    u16* qphh = (u16*)(wsp + 35 * MB);  u16* qpll = (u16*)(wsp + 39 * MB);
    u16* vphh = (u16*)(wsp + 43 * MB);  u16* vpll = (u16*)(wsp + 47 * MB);
    u16* Vth  = (u16*)(wsp + 51 * MB);  u16* Vtl  = (u16*)(wsp + 55 * MB);
    u16* kphh = xph;                    u16* kpll = xpl;   // li 0,1 only (xp not live yet)
    float* t1 = (float*)(wsp + 35 * MB);                   // qp region, after attn
    u16* ffh  = (u16*)(wsp + 43 * MB);  u16* ffl  = (u16*)(wsp + 51 * MB);  // vp+Vt, after Wo
    // head
    u16* hch = (u16*)(wsp + 24 * MB);   u16* hcl = (u16*)(wsp + 32 * MB);
    u16* bH0h = (u16*)(wsp + 40 * MB);  u16* bH0l = (u16*)(wsp + 41 * MB);
    u16* bH1h = (u16*)(wsp + 42 * MB);  u16* bH1l = (u16*)(wsp + 43 * MB);
    u16* bH2h = (u16*)(wsp + 44 * MB);  u16* bH2l = (u16*)(wsp + 46 * MB);
    u16* h1ph = (u16*)(wsp + 48 * MB);  u16* h1pl = (u16*)(wsp + 52 * MB);
    u16* h2ph = (u16*)(wsp + 24 * MB);  u16* h2pl = (u16*)(wsp + 32 * MB);

    embed_pl<<<dim3(TOK), dim3(256), 0, stream>>>(c_data, ca_data, c_emb, ca_emb,
                                                  x0ph, x0pl, yph, ypl);

    for (int li = 0; li < 6; ++li) {
        int pos = (li != 2 && li != 4);
        int m0 = (li == 3 || li == 5);

        wsplit_layer<<<dim3(pos ? 704 : 192), dim3(256), 0, stream>>>(
            Wk + (size_t)li * DIM * DIM, Wv + (size_t)li * DIM * DIM,
            Wo + (size_t)li * DIM * DIM,
            W1 + (size_t)li * DIM * FFD, W2 + (size_t)li * FFD * DIM,
            btQVh, btQVl, btWoh, btWol, btW1h, btW1l, btW2h, btW2l);

        const u16 *Kph, *Kpl;
        const u16 *residH, *residL; u16 *outH, *outL;
        if (li == 0 || li == 1) {
            // qv fused (A=y) + k (A=x0) in one dual-slot launch
            GD dqv = mkgd(yph, ypl, btQVh, btQVl, DIM, DIM, 0,
                          bk + li * DIM, bv + li * DIM, 1024, EP_PL | EP_QV,
                          nullptr, qphh, qpll, vphh, vpll);
            GD dk = mkgd(x0ph, x0pl, btQVh, btQVl, DIM, DIM, 0,
                         bk + li * DIM, nullptr, DIM, EP_PL,
                         nullptr, kphh, kpll, nullptr, nullptr);
            run_gemm2(dqv, dk, stream);
            Kph = kphh; Kpl = kpll;
            residH = yph; residL = ypl; outH = yph; outL = ypl;
        } else if (li == 2 || li == 4) {
            const u16* ah = (li == 2) ? x0ph : xph;
            const u16* al = (li == 2) ? x0pl : xpl;
            GD dqv = mkgd(ah, al, btQVh, btQVl, DIM, DIM, 0,
                          bk + li * DIM, bv + li * DIM, 1024, EP_PL | EP_QV,
                          nullptr, qphh, qpll, vphh, vpll);
            run_gemm1(dqv, stream);
            Kph = qphh; Kpl = qpll;
            residH = (li == 2) ? x0ph : xph; residL = (li == 2) ? x0pl : xpl;
            outH = xph; outL = xpl;
        } else {
            // q (A=x) + v (A=y) dual-slot
            GD dq = mkgd(xph, xpl, btQVh, btQVl, DIM, DIM, 0,
                         bk + li * DIM, nullptr, DIM, EP_PL,
                         nullptr, qphh, qpll, nullptr, nullptr);
            GD dv = mkgd(yph, ypl, btQVh + 512 * 512, btQVl + 512 * 512, DIM, DIM, 0,
                         bv + li * DIM, nullptr, DIM, EP_PL,
                         nullptr, vphh, vpll, nullptr, nullptr);
            run_gemm2(dq, dv, stream);
            Kph = qphh; Kpl = qpll;
            residH = xph; residL = xpl; outH = xph; outL = xpl;
        }

        vtsplit_pp<<<dim3(SEQ / 64, BATCH * NHEAD), dim3(256), 0, stream>>>(vphh, vpll, Vth, Vtl);
        attn_mf<<<dim3(8, NHEAD, BATCH), dim3(256), 0, stream>>>(
            qphh, qpll, Kph, Kpl, Vth, Vtl, gammas + li * NHEAD, vphh, vpll, m0);

        GD dwo = mkgd(vphh, vpll, btWoh, btWol, DIM, DIM, 0,
                      bo + li * DIM, nullptr, DIM, EP_F32,
                      t1, nullptr, nullptr, nullptr, nullptr);
        run_gemm1(dwo, stream);
        add_ln_pl<<<dim3(TOK / 4), dim3(256), 0, stream>>>(residH, residL, t1,
                                                           ln1s + li * DIM, ln1b + li * DIM,
                                                           outH, outL);
        if (pos) {
            for (int c = 0; c < 2; ++c) {
                GD d1c = mkgd(outH, outL,
                              btW1h + (size_t)c * 1024 * DIM, btW1l + (size_t)c * 1024 * DIM,
                              DIM, DIM, 0, b1 + li * FFD + c * 1024, nullptr,
                              1024, EP_RELU | EP_PL, nullptr, ffh, ffl, nullptr, nullptr);
                run_gemm1(d1c, stream);
                GD d2c = mkgd(ffh, ffl, btW2h, btW2l, 1024, FFD, c * 1024,
                              b2 + li * DIM, nullptr, DIM,
                              (c == 0) ? EP_F32 : (EP_F32 | EP_ACC),
                              t1, nullptr, nullptr, nullptr, nullptr);
                run_gemm1(d2c, stream);
            }
            add_ln_pl<<<dim3(TOK / 4), dim3(256), 0, stream>>>(outH, outL, t1,
                                                               ln2s + li * DIM, ln2b + li * DIM,
                                                               outH, outL);
        }
    }

    concat_pl<<<dim3(TOK), dim3(256), 0, stream>>>(xph, xpl, x0ph, x0pl, hch, hcl);
    wsplit_head<<<dim3(512), dim3(256), 0, stream>>>(oW0, oW1, oW2,
                                                     bH0h, bH0l, bH1h, bH1l, bH2h, bH2l);
    GD g0 = mkgd(hch, hcl, bH0h, bH0l, 1024, 1024, 0, ob0, nullptr, 512,
                 EP_RELU | EP_PL, nullptr, h1ph, h1pl, nullptr, nullptr);
    run_gemm1(g0, stream);
    GD g1 = mkgd(h1ph, h1pl, bH1h, bH1l, 512, 512, 0, ob1, nullptr, 1024,
                 EP_RELU | EP_PL, nullptr, h2ph, h2pl, nullptr, nullptr);
    run_gemm1(g1, stream);
    GD g2 = mkgd(h2ph, h2pl, bH2h, bH2l, 1024, 1024, 0, ob2, nullptr, 1000,
                 EP_F32, out, nullptr, nullptr, nullptr, nullptr);
    run_gemm1(g2, stream);
}

// Round 6
// 1300.977 us; speedup vs baseline: 1.3246x; 1.0932x over previous
//
#include <hip/hip_runtime.h>

#define TOK 4096
#define SEQ 512
#define BATCH 8
#define DIM 512
#define NHEAD 8
#define DK 64
#define FFD 2048

typedef unsigned short u16;
typedef unsigned int u32;
typedef float floatx4 __attribute__((ext_vector_type(4)));
typedef short shortx8 __attribute__((ext_vector_type(8)));

// epilogue mode bits
#define EP_RELU 1
#define EP_ACC  2
#define EP_F32  4
#define EP_PL   8
#define EP_QV  16
#define EP_VT  32

__device__ __forceinline__ u16 bfh(float f) {
    union { float f; unsigned u; } x; x.f = f;
    return (u16)((x.u + 0x7fffu + ((x.u >> 16) & 1u)) >> 16);
}
__device__ __forceinline__ float bff(u16 h) {
    union { unsigned u; float f; } x; x.u = (unsigned)h << 16; return x.f;
}
// truncation-based hi/lo split: residual ~2^-16 relative
__device__ __forceinline__ void bfsplit(float v, u16& h, u16& l) {
    union { float f; unsigned u; } x; x.f = v;
    union { unsigned u; float f; } hb; hb.u = x.u & 0xffff0000u;
    float rem = v - hb.f;
    union { float f; unsigned u; } rr; rr.f = rem;
    h = (u16)(x.u >> 16);
    l = (u16)(rr.u >> 16);
}
__device__ __forceinline__ float rec2(u16 h, u16 l) { return bff(h) + bff(l); }
__device__ __forceinline__ float wave_sum(float v) {
    #pragma unroll
    for (int off = 32; off; off >>= 1) v += __shfl_xor(v, off, 64);
    return v;
}

#define GLDS16(gp, lp) __builtin_amdgcn_global_load_lds( \
    (const __attribute__((address_space(1))) u32*)(const void*)(gp), \
    (__attribute__((address_space(3))) u32*)(void*)(lp), 16, 0, 0)

// sentinel: ws too small
__global__ void VAKT_52226802319686_kernel(float* out, int n) {
    int i = blockIdx.x * 256 + threadIdx.x;
    if (i < n) out[i] = 524288.f;
}

__global__ void embed_pl(const int* cd, const int* cad, const float* cemb,
                         const float* caemb,
                         u16* x0h, u16* x0l, u16* yh, u16* yl) {
    int tok = blockIdx.x;
    int idx = cd[tok];
    int resp = (cad[tok] - idx) / 1000;
    for (int d = threadIdx.x; d < DIM; d += 256) {
        float e = cemb[(size_t)idx * DIM + d];
        float yv = e + caemb[resp * DIM + d];
        size_t o = (size_t)tok * DIM + d;
        u16 hh, ll;
        bfsplit(e, hh, ll);  x0h[o] = hh; x0l[o] = ll;
        bfsplit(yv, hh, ll); yh[o] = hh;  yl[o] = ll;
    }
}

__global__ void concat_pl(const u16* Xh, const u16* Xl, const u16* X0h, const u16* X0l,
                          u16* Hh, u16* Hl) {
    int tok = blockIdx.x;
    for (int d = threadIdx.x; d < 2 * DIM; d += 256) {
        size_t s = (size_t)tok * DIM + ((d < DIM) ? d : d - DIM);
        size_t o = (size_t)tok * (2 * DIM) + d;
        Hh[o] = (d < DIM) ? Xh[s] : X0h[s];
        Hl[o] = (d < DIM) ? Xl[s] : X0l[s];
    }
}

// resid from planes + f32 delta -> LN -> planes out (in-place safe per-row)
__global__ void add_ln_pl(const u16* Xh, const u16* Xl, const float* Dl,
                          const float* sc, const float* bi, u16* Oh, u16* Ol) {
    int lane = threadIdx.x & 63, w = threadIdx.x >> 6;
    size_t row = (size_t)blockIdx.x * 4 + w;
    const u16* xh = Xh + row * DIM;
    const u16* xl = Xl + row * DIM;
    const float* dr = Dl + row * DIM;
    float v[8]; float sum = 0.f, sq = 0.f;
    for (int i = 0; i < 8; i++) {
        int d = i * 64 + lane;
        float t = rec2(xh[d], xl[d]) + dr[d];
        v[i] = t; sum += t; sq += t * t;
    }
    sum = wave_sum(sum); sq = wave_sum(sq);
    float mean = sum * (1.0f / 512.0f);
    float var = sq * (1.0f / 512.0f) - mean * mean;
    float rstd = rsqrtf(var + 1e-5f);
    for (int i = 0; i < 8; i++) {
        int d = i * 64 + lane;
        float val = (v[i] - mean) * rstd * sc[d] + bi[d];
        u16 hh, ll; bfsplit(val, hh, ll);
        Oh[row * DIM + d] = hh; Ol[row * DIM + d] = ll;
    }
}

// one 64x64 transpose+split tile: W[K][N] fp32 -> dst [Npad][K] u16 hi/lo
__device__ __forceinline__ void wtile_body(float (*T)[65], const float* W, int K, int N,
                                           int k0, int n0, u16* dh, u16* dl) {
    int t = threadIdx.x;
    for (int i = 0; i < 16; i++) {
        int idx = i * 256 + t;
        int kr = idx >> 6, nc = idx & 63;
        int gn = n0 + nc;
        T[kr][nc] = (gn < N) ? W[(size_t)(k0 + kr) * N + gn] : 0.f;
    }
    __syncthreads();
    for (int i = 0; i < 16; i++) {
        int idx = i * 256 + t;
        int nr = idx >> 6, kc = idx & 63;
        float v = T[kc][nr];
        u16 h = bfh(v);
        float rem = v - bff(h);
        size_t o = (size_t)(n0 + nr) * K + k0 + kc;
        dh[o] = h; dl[o] = bfh(rem);
    }
}

// all weight splits for one layer in a single launch.
// grid 192 (Wk,Wv,Wo) or 704 (+W1,W2)
__global__ __launch_bounds__(256) void wsplit_layer(
    const float* Wk, const float* Wv, const float* Wo,
    const float* W1, const float* W2,
    u16* qvh, u16* qvl, u16* woh, u16* wol,
    u16* w1h, u16* w1l, u16* w2h, u16* w2l) {
    __shared__ float T[64][65];
    int bid = blockIdx.x;
    if (bid < 192) {
        int m = bid >> 6, t2 = bid & 63;
        int k0 = (t2 & 7) * 64, n0 = (t2 >> 3) * 64;
        const float* W = (m == 0) ? Wk : (m == 1) ? Wv : Wo;
        u16* dh = (m == 0) ? qvh : (m == 1) ? (qvh + 512 * 512) : woh;
        u16* dl = (m == 0) ? qvl : (m == 1) ? (qvl + 512 * 512) : wol;
        wtile_body(T, W, 512, 512, k0, n0, dh, dl);
    } else if (bid < 448) {
        int t2 = bid - 192;
        wtile_body(T, W1, 512, 2048, (t2 & 7) * 64, (t2 >> 3) * 64, w1h, w1l);
    } else {
        int t2 = bid - 448;
        wtile_body(T, W2, 2048, 512, (t2 & 31) * 64, (t2 >> 5) * 64, w2h, w2l);
    }
}

// head weight splits: oW0 (1024x512), oW1 (512x1024), oW2 (1024x1000->pad1024). grid 512
__global__ __launch_bounds__(256) void wsplit_head(
    const float* oW0, const float* oW1, const float* oW2,
    u16* h0h, u16* h0l, u16* h1h, u16* h1l, u16* h2h, u16* h2l) {
    __shared__ float T[64][65];
    int bid = blockIdx.x;
    if (bid < 128) {
        wtile_body(T, oW0, 1024, 512, (bid & 15) * 64, (bid >> 4) * 64, h0h, h0l);
    } else if (bid < 256) {
        int t2 = bid - 128;
        wtile_body(T, oW1, 512, 1024, (t2 & 7) * 64, (t2 >> 3) * 64, h1h, h1l);
    } else {
        int t2 = bid - 256;
        wtile_body(T, oW2, 1024, 1000, (t2 & 15) * 64, (t2 >> 4) * 64, h2h, h2l);
    }
}

struct GD {
    const u16 *Ah, *Al, *Bh, *Bl;
    const float *bias, *bias2;
    float* Cf; u16 *Ch, *Cl, *Ch2, *Cl2;
    int K, Bstride, Boff, N, mode;
};

// C[4096,N] = A @ Bt^T (+bias). dual problem slots via blockIdx.z.
// EP_VT: V-columns written directly to Vt[bh][64 d][512 s] (hi in Ch2, lo in Cl2).
__global__ __launch_bounds__(256) void gemm_pp(GD d0, GD d1) {
    const GD d = blockIdx.z ? d1 : d0;
    const int bn0 = blockIdx.x * 64;
    if (bn0 >= ((d.N + 63) & ~63)) return;
    __shared__ u16 sm[24576];
    const int t = threadIdx.x;
    const int lane = t & 63, w = t >> 6;
    const int l16 = lane & 15, quad = lane >> 4;
    const int bm0 = blockIdx.y * 128;
    const int wm = (w & 1) * 64, wn = (w >> 1) * 32;

    floatx4 acc[4][2];
    #pragma unroll
    for (int mi = 0; mi < 4; mi++)
        #pragma unroll
        for (int ni = 0; ni < 2; ni++) acc[mi][ni] = (floatx4){0.f, 0.f, 0.f, 0.f};

    for (int k0 = 0; k0 < d.K; k0 += 64) {
        __syncthreads();
        #pragma unroll
        for (int p = 0; p < 2; ++p) {
            const u16* Asrc = p ? d.Al : d.Ah;
            #pragma unroll
            for (int rr = 0; rr < 4; ++rr) {
                int idx = (rr * 4 + w) * 64 + lane;
                int row = idx >> 3;
                int sg = (idx & 7) ^ (row & 7);
                const u16* gp = Asrc + (size_t)(bm0 + row) * d.K + k0 + sg * 8;
                u16* lp = sm + p * 8192 + (rr * 4 + w) * 512;
                GLDS16(gp, lp);
            }
        }
        #pragma unroll
        for (int p = 0; p < 2; ++p) {
            const u16* Bsrc = p ? d.Bl : d.Bh;
            #pragma unroll
            for (int rr = 0; rr < 2; ++rr) {
                int idx = (rr * 4 + w) * 64 + lane;
                int row = idx >> 3;
                int sg = (idx & 7) ^ (row & 7);
                const u16* gp = Bsrc + (size_t)(bn0 + row) * d.Bstride + d.Boff + k0 + sg * 8;
                u16* lp = sm + 16384 + p * 4096 + (rr * 4 + w) * 512;
                GLDS16(gp, lp);
            }
        }
        __syncthreads();
        #pragma unroll
        for (int ks = 0; ks < 2; ++ks) {
            shortx8 ah[4], al[4], bh2[2], bl2[2];
            #pragma unroll
            for (int mi = 0; mi < 4; ++mi) {
                int row = wm + mi * 16 + l16;
                int s = (ks * 4 + quad) ^ (row & 7);
                ah[mi] = *(const shortx8*)&sm[row * 64 + s * 8];
                al[mi] = *(const shortx8*)&sm[8192 + row * 64 + s * 8];
            }
            #pragma unroll
            for (int ni = 0; ni < 2; ++ni) {
                int row = wn + ni * 16 + l16;
                int s = (ks * 4 + quad) ^ (row & 7);
                bh2[ni] = *(const shortx8*)&sm[16384 + row * 64 + s * 8];
                bl2[ni] = *(const shortx8*)&sm[20480 + row * 64 + s * 8];
            }
            #pragma unroll
            for (int mi = 0; mi < 4; ++mi)
                #pragma unroll
                for (int ni = 0; ni < 2; ++ni) {
                    acc[mi][ni] = __builtin_amdgcn_mfma_f32_16x16x32_bf16(ah[mi], bh2[ni], acc[mi][ni], 0, 0, 0);
                    acc[mi][ni] = __builtin_amdgcn_mfma_f32_16x16x32_bf16(ah[mi], bl2[ni], acc[mi][ni], 0, 0, 0);
                    acc[mi][ni] = __builtin_amdgcn_mfma_f32_16x16x32_bf16(al[mi], bh2[ni], acc[mi][ni], 0, 0, 0);
                }
        }
    }
    #pragma unroll
    for (int ni = 0; ni < 2; ++ni) {
        int col = bn0 + wn + ni * 16 + l16;
        if (col < d.N) {
            float bv;
            if (d.mode & EP_ACC) bv = 0.f;
            else if ((d.mode & EP_QV) && col >= 512) bv = d.bias2[col - 512];
            else bv = d.bias[col];
            bool vt = (d.mode & EP_VT) && (!(d.mode & EP_QV) || col >= 512);
            if (vt) {
                int vcol = (d.mode & EP_QV) ? col - 512 : col;
                int hidx = vcol >> 6, dd = vcol & 63;
                #pragma unroll
                for (int mi = 0; mi < 4; ++mi) {
                    int row0 = bm0 + wm + mi * 16 + quad * 4;
                    int bb = row0 >> 9, s0 = row0 & 511;
                    size_t base = (((size_t)(bb * NHEAD + hidx) * 64) + dd) * SEQ + s0;
                    u16 hh4[4], ll4[4];
                    #pragma unroll
                    for (int r = 0; r < 4; ++r) {
                        float v = acc[mi][ni][r] + bv;
                        bfsplit(v, hh4[r], ll4[r]);
                    }
                    uint2 hw, lw;
                    hw.x = (u32)hh4[0] | ((u32)hh4[1] << 16);
                    hw.y = (u32)hh4[2] | ((u32)hh4[3] << 16);
                    lw.x = (u32)ll4[0] | ((u32)ll4[1] << 16);
                    lw.y = (u32)ll4[2] | ((u32)ll4[3] << 16);
                    *(uint2*)(d.Ch2 + base) = hw;
                    *(uint2*)(d.Cl2 + base) = lw;
                }
            } else {
                #pragma unroll
                for (int mi = 0; mi < 4; ++mi) {
                    #pragma unroll
                    for (int r = 0; r < 4; ++r) {
                        int row = bm0 + wm + mi * 16 + quad * 4 + r;
                        float v = acc[mi][ni][r] + bv;
                        if ((d.mode & EP_RELU) && v < 0.f) v = 0.f;
                        if (d.mode & EP_ACC) v += d.Cf[(size_t)row * d.N + col];
                        if (d.mode & EP_F32) d.Cf[(size_t)row * d.N + col] = v;
                        if (d.mode & EP_PL) {
                            u16 hh, ll; bfsplit(v, hh, ll);
                            size_t o = (size_t)row * ((d.mode & EP_QV) ? 512 : d.N) + col;
                            d.Ch[o] = hh; d.Cl[o] = ll;
                        }
                    }
                }
            }
        }
    }
}

// MFMA attention. One block = 64 q-rows of one (b,h), 4 waves x 16 rows.
// Grid (64 bh, 8 chunk-order): linear%8 == h -> all blocks sharing this
// (b,h)'s K/Vt land on ONE XCD; per-XCD working set (~2 MB) is L2-resident.
// K/V staged chunk-wise into LDS via global_load_lds (linear dest, source-side
// XOR swizzle; reads use the same swizzle).
__global__ __launch_bounds__(256, 2) void attn_mf(
    const u16* __restrict__ Qh, const u16* __restrict__ Ql,
    const u16* __restrict__ Kh, const u16* __restrict__ Kl,
    const u16* __restrict__ Vth, const u16* __restrict__ Vtl,
    const float* __restrict__ gam, u16* __restrict__ AOh, u16* __restrict__ AOl,
    int m0) {
    __shared__ __align__(16) u16 KV[8192];            // [2 planes][64 rows][64] linear
    __shared__ __align__(16) u16 PB[4][2][16][72];    // per-wave P repack
    const int t = threadIdx.x;
    const int lane = t & 63, w = t >> 6;
    const int l16 = lane & 15, quad = lane >> 4;
    const int bxi = (int)blockIdx.x;                  // b*8+h -> XCD = h
    const int h = bxi & 7, b = bxi >> 3;
    const int chunk = 7 - (int)blockIdx.y;            // heavy blocks dispatch first
    const int bS = b * SEQ;
    const int bh = b * NHEAD + h;
    const int nch = chunk + 1, nkt = nch * 4;
    const int qrow0 = chunk * 64 + w * 16;
    const int qrow = qrow0 + l16;
    const int kmax = qrow - m0;

    float g = gam[h];
    float gamma = -((g > 20.f) ? g : log1pf(__expf(g)));

    shortx8 qh[2], ql[2];
    {
        const u16* qph = Qh + (size_t)(bS + qrow) * DIM + h * 64;
        const u16* qpl = Ql + (size_t)(bS + qrow) * DIM + h * 64;
        #pragma unroll
        for (int ks = 0; ks < 2; ++ks) {
            qh[ks] = *(const shortx8*)(qph + ks * 32 + quad * 8);
            ql[ks] = *(const shortx8*)(qpl + ks * 32 + quad * 8);
        }
    }

    floatx4 s[32];
    #pragma unroll
    for (int i = 0; i < 32; ++i) s[i] = (floatx4){0.f, 0.f, 0.f, 0.f};

    // ---- Phase 1: scoresT = K . Q^T over causal key chunks ----
    #pragma unroll
    for (int c = 0; c < 8; ++c) {
        if (c < nch) {
            __syncthreads();
            #pragma unroll
            for (int p = 0; p < 2; ++p) {
                const u16* src = p ? Kl : Kh;
                #pragma unroll
                for (int rr = 0; rr < 2; ++rr) {
                    int idx = (rr * 4 + w) * 64 + lane;   // 0..511
                    int row = idx >> 3;
                    int sg = (idx & 7) ^ (row & 7);
                    const u16* gp = src + (size_t)(bS + c * 64 + row) * DIM + h * 64 + sg * 8;
                    u16* lp = KV + p * 4096 + (rr * 4 + w) * 512;
                    GLDS16(gp, lp);
                }
            }
            __syncthreads();
            #pragma unroll
            for (int kt = 0; kt < 4; ++kt) {
                int row = kt * 16 + l16;
                int s0i = (quad ^ (row & 7)) * 8;
                int s1i = ((4 + quad) ^ (row & 7)) * 8;
                shortx8 kh0 = *(const shortx8*)&KV[row * 64 + s0i];
                shortx8 kh1 = *(const shortx8*)&KV[row * 64 + s1i];
                shortx8 kl0 = *(const shortx8*)&KV[4096 + row * 64 + s0i];
                shortx8 kl1 = *(const shortx8*)&KV[4096 + row * 64 + s1i];
                floatx4 a = s[c * 4 + kt];
                a = __builtin_amdgcn_mfma_f32_16x16x32_bf16(kh0, qh[0], a, 0, 0, 0);
                a = __builtin_amdgcn_mfma_f32_16x16x32_bf16(kh1, qh[1], a, 0, 0, 0);
                a = __builtin_amdgcn_mfma_f32_16x16x32_bf16(kh0, ql[0], a, 0, 0, 0);
                a = __builtin_amdgcn_mfma_f32_16x16x32_bf16(kh1, ql[1], a, 0, 0, 0);
                a = __builtin_amdgcn_mfma_f32_16x16x32_bf16(kl0, qh[0], a, 0, 0, 0);
                a = __builtin_amdgcn_mfma_f32_16x16x32_bf16(kl1, qh[1], a, 0, 0, 0);
                s[c * 4 + kt] = a;
            }
        }
    }

    // ---- Phase 2: softmax -> cumsum decay -> second softmax (registers) ----
    float m1 = -1e30f;
    #pragma unroll
    for (int kt = 0; kt < 32; ++kt) {
        if (kt < nkt) {
            #pragma unroll
            for (int r = 0; r < 4; ++r) {
                int key = kt * 16 + quad * 4 + r;
                float sv = (key <= kmax) ? s[kt][r] * 0.125f : -1e30f;
                s[kt][r] = sv;
                m1 = fmaxf(m1, sv);
            }
        }
    }
    m1 = fmaxf(m1, __shfl_xor(m1, 16, 64));
    m1 = fmaxf(m1, __shfl_xor(m1, 32, 64));

    float sum1 = 0.f;
    #pragma unroll
    for (int kt = 0; kt < 32; ++kt) {
        if (kt < nkt) {
            #pragma unroll
            for (int r = 0; r < 4; ++r) sum1 += __expf(s[kt][r] - m1);
        }
    }
    sum1 += __shfl_xor(sum1, 16, 64);
    sum1 += __shfl_xor(sum1, 32, 64);
    float inv1 = 1.f / sum1;

    float carry = 0.f, m2 = -1e30f;
    #pragma unroll
    for (int kt = 0; kt < 32; ++kt) {
        if (kt < nkt) {
            float e0 = __expf(s[kt][0] - m1);
            float e1 = __expf(s[kt][1] - m1);
            float e2 = __expf(s[kt][2] - m1);
            float e3 = __expf(s[kt][3] - m1);
            float c0 = e0, c1 = c0 + e1, c2 = c1 + e2, c3 = c2 + e3;
            float q0 = __shfl(c3, l16, 64);
            float q1 = __shfl(c3, l16 + 16, 64);
            float q2 = __shfl(c3, l16 + 32, 64);
            float q3 = __shfl(c3, l16 + 48, 64);
            float excl = carry;
            if (quad > 0) excl += q0;
            if (quad > 1) excl += q1;
            if (quad > 2) excl += q2;
            carry += q0 + q1 + q2 + q3;
            float cc[4] = {c0, c1, c2, c3};
            #pragma unroll
            for (int r = 0; r < 4; ++r) {
                int key = kt * 16 + quad * 4 + r;
                float distcum = (excl + cc[r]) * inv1;
                float rem = fmaxf(1.f - distcum, 0.f);
                float prod = fmaxf(rem * (float)(qrow - key), 0.f);
                float te = fmaxf(__expf(sqrtf(prod) * gamma), 1e-5f);
                te = fminf(te, 1e5f);
                float sv2 = s[kt][r] * te;
                s[kt][r] = sv2;
                m2 = fmaxf(m2, sv2);
            }
        }
    }
    m2 = fmaxf(m2, __shfl_xor(m2, 16, 64));
    m2 = fmaxf(m2, __shfl_xor(m2, 32, 64));

    float sum2 = 0.f;
    #pragma unroll
    for (int kt = 0; kt < 32; ++kt) {
        if (kt < nkt) {
            #pragma unroll
            for (int r = 0; r < 4; ++r) {
                float p = __expf(s[kt][r] - m2);
                s[kt][r] = p;
                sum2 += p;
            }
        }
    }
    sum2 += __shfl_xor(sum2, 16, 64);
    sum2 += __shfl_xor(sum2, 32, 64);
    float inv2 = 1.f / sum2;

    // ---- Phase 3: O = P . V over causal key chunks ----
    floatx4 o[4];
    #pragma unroll
    for (int i = 0; i < 4; ++i) o[i] = (floatx4){0.f, 0.f, 0.f, 0.f};

    #pragma unroll
    for (int c = 0; c < 8; ++c) {
        if (c < nch) {
            __syncthreads();
            // issue V staging (async); P repack below overlaps its latency
            #pragma unroll
            for (int p = 0; p < 2; ++p) {
                const u16* src = p ? Vtl : Vth;
                #pragma unroll
                for (int rr = 0; rr < 2; ++rr) {
                    int idx = (rr * 4 + w) * 64 + lane;
                    int row = idx >> 3;
                    int sg = (idx & 7) ^ (row & 7);
                    const u16* gp = src + ((size_t)bh * 64 + row) * SEQ + c * 64 + sg * 8;
                    u16* lp = KV + p * 4096 + (rr * 4 + w) * 512;
                    GLDS16(gp, lp);
                }
            }
            // repack this chunk of P into A-fragment layout (per-wave LDS)
            #pragma unroll
            for (int kt = 0; kt < 4; ++kt) {
                floatx4 pv = s[c * 4 + kt];
                u16 hh[4], ll[4];
                #pragma unroll
                for (int r = 0; r < 4; ++r) bfsplit(pv[r] * inv2, hh[r], ll[r]);
                uint2 hw, lw;
                hw.x = (unsigned)hh[0] | ((unsigned)hh[1] << 16);
                hw.y = (unsigned)hh[2] | ((unsigned)hh[3] << 16);
                lw.x = (unsigned)ll[0] | ((unsigned)ll[1] << 16);
                lw.y = (unsigned)ll[2] | ((unsigned)ll[3] << 16);
                *(uint2*)&PB[w][0][l16][kt * 16 + quad * 4] = hw;
                *(uint2*)&PB[w][1][l16][kt * 16 + quad * 4] = lw;
            }
            __syncthreads();
            shortx8 ph0 = *(const shortx8*)&PB[w][0][l16][quad * 8];
            shortx8 ph1 = *(const shortx8*)&PB[w][0][l16][32 + quad * 8];
            shortx8 pl0 = *(const shortx8*)&PB[w][1][l16][quad * 8];
            shortx8 pl1 = *(const shortx8*)&PB[w][1][l16][32 + quad * 8];
            #pragma unroll
            for (int dt = 0; dt < 4; ++dt) {
                int row = dt * 16 + l16;
                int s0i = (quad ^ (row & 7)) * 8;
                int s1i = ((4 + quad) ^ (row & 7)) * 8;
                shortx8 vh0 = *(const shortx8*)&KV[row * 64 + s0i];
                shortx8 vh1 = *(const shortx8*)&KV[row * 64 + s1i];
                shortx8 vl0 = *(const shortx8*)&KV[4096 + row * 64 + s0i];
                shortx8 vl1 = *(const shortx8*)&KV[4096 + row * 64 + s1i];
                floatx4 a = o[dt];
                a = __builtin_amdgcn_mfma_f32_16x16x32_bf16(ph0, vh0, a, 0, 0, 0);
                a = __builtin_amdgcn_mfma_f32_16x16x32_bf16(ph1, vh1, a, 0, 0, 0);
                a = __builtin_amdgcn_mfma_f32_16x16x32_bf16(ph0, vl0, a, 0, 0, 0);
                a = __builtin_amdgcn_mfma_f32_16x16x32_bf16(ph1, vl1, a, 0, 0, 0);
                a = __builtin_amdgcn_mfma_f32_16x16x32_bf16(pl0, vh0, a, 0, 0, 0);
                a = __builtin_amdgcn_mfma_f32_16x16x32_bf16(pl1, vh1, a, 0, 0, 0);
                o[dt] = a;
            }
        }
    }

    #pragma unroll
    for (int dt = 0; dt < 4; ++dt) {
        #pragma unroll
        for (int r = 0; r < 4; ++r) {
            int row = qrow0 + quad * 4 + r;
            float v = o[dt][r];
            if (m0 && row == 0) v = 0.f;
            u16 hh, ll; bfsplit(v, hh, ll);
            size_t oo = (size_t)(bS + row) * DIM + h * 64 + dt * 16 + l16;
            AOh[oo] = hh; AOl[oo] = ll;
        }
    }
}

static GD mkgd(const u16* Ah, const u16* Al, const u16* Bh, const u16* Bl,
               int K, int Bstride, int Boff, const float* bias, const float* bias2,
               int N, int mode, float* Cf, u16* Ch, u16* Cl, u16* Ch2, u16* Cl2) {
    GD d; d.Ah = Ah; d.Al = Al; d.Bh = Bh; d.Bl = Bl; d.bias = bias; d.bias2 = bias2;
    d.Cf = Cf; d.Ch = Ch; d.Cl = Cl; d.Ch2 = Ch2; d.Cl2 = Cl2;
    d.K = K; d.Bstride = Bstride; d.Boff = Boff; d.N = N; d.mode = mode;
    return d;
}
static void run_gemm1(const GD& d, hipStream_t stream) {
    dim3 g(((d.N + 63) & ~63) / 64, TOK / 128, 1);
    gemm_pp<<<g, dim3(256), 0, stream>>>(d, d);
}
static void run_gemm2(const GD& d0, const GD& d1, hipStream_t stream) {
    int n0 = (d0.N + 63) & ~63, n1 = (d1.N + 63) & ~63;
    dim3 g(((n0 > n1 ? n0 : n1)) / 64, TOK / 128, 2);
    gemm_pp<<<g, dim3(256), 0, stream>>>(d0, d1);
}

extern "C" void kernel_launch(void* const* d_in, const int* in_sizes, int n_in,
                              void* d_out, int out_size, void* d_ws, size_t ws_size,
                              hipStream_t stream) {
    (void)in_sizes; (void)n_in;
    const int* c_data    = (const int*)d_in[0];
    const int* ca_data   = (const int*)d_in[1];
    const float* c_emb   = (const float*)d_in[2];
    const float* ca_emb  = (const float*)d_in[3];
    const float* Wk  = (const float*)d_in[4];
    const float* bk  = (const float*)d_in[5];
    const float* Wv  = (const float*)d_in[6];
    const float* bv  = (const float*)d_in[7];
    const float* Wo  = (const float*)d_in[8];
    const float* bo  = (const float*)d_in[9];
    const float* gammas = (const float*)d_in[10];
    const float* ln1s = (const float*)d_in[11];
    const float* ln1b = (const float*)d_in[12];
    const float* W1  = (const float*)d_in[13];
    const float* b1  = (const float*)d_in[14];
    const float* W2  = (const float*)d_in[15];
    const float* b2  = (const float*)d_in[16];
    const float* ln2s = (const float*)d_in[17];
    const float* ln2b = (const float*)d_in[18];
    const float* oW0 = (const float*)d_in[19];
    const float* ob0 = (const float*)d_in[20];
    const float* oW1 = (const float*)d_in[21];
    const float* ob1 = (const float*)d_in[22];
    const float* oW2 = (const float*)d_in[23];
    const float* ob2 = (const float*)d_in[24];

    float* out = (float*)d_out;
    const size_t MB = 1024 * 1024;
    if (ws_size < 64 * MB) {
        VAKT_52226802319686_kernel<<<dim3((out_size + 255) / 256), dim3(256), 0, stream>>>(out, out_size);
        return;
    }
    char* wsp = (char*)d_ws;
    // persistent activation planes
    u16* x0ph = (u16*)(wsp);            u16* x0pl = (u16*)(wsp + 4 * MB);
    u16* yph  = (u16*)(wsp + 8 * MB);   u16* ypl  = (u16*)(wsp + 12 * MB);
    u16* xph  = (u16*)(wsp + 16 * MB);  u16* xpl  = (u16*)(wsp + 20 * MB);
    // per-layer weight planes [24,35)
    u16* btQVh = (u16*)(wsp + 24 * MB); u16* btQVl = (u16*)(wsp + 25 * MB);
    u16* btWoh = (u16*)(wsp + 26 * MB); u16* btWol = (u16*)(wsp + 26 * MB + 512 * 1024);
    u16* btW1h = (u16*)(wsp + 27 * MB); u16* btW1l = (u16*)(wsp + 29 * MB);
    u16* btW2h = (u16*)(wsp + 31 * MB); u16* btW2l = (u16*)(wsp + 33 * MB);
    // per-layer activation scratch
    u16* qphh = (u16*)(wsp + 35 * MB);  u16* qpll = (u16*)(wsp + 39 * MB);
    u16* vphh = (u16*)(wsp + 43 * MB);  u16* vpll = (u16*)(wsp + 47 * MB);
    u16* Vth  = (u16*)(wsp + 51 * MB);  u16* Vtl  = (u16*)(wsp + 55 * MB);
    u16* kphh = xph;                    u16* kpll = xpl;   // li 0,1 only (xp not live yet)
    float* t1 = (float*)(wsp + 35 * MB);                   // qp region, after attn
    u16* ffh  = (u16*)(wsp + 43 * MB);  u16* ffl  = (u16*)(wsp + 51 * MB);  // vp+Vt, after Wo
    // head
    u16* hch = (u16*)(wsp + 24 * MB);   u16* hcl = (u16*)(wsp + 32 * MB);
    u16* bH0h = (u16*)(wsp + 40 * MB);  u16* bH0l = (u16*)(wsp + 41 * MB);
    u16* bH1h = (u16*)(wsp + 42 * MB);  u16* bH1l = (u16*)(wsp + 43 * MB);
    u16* bH2h = (u16*)(wsp + 44 * MB);  u16* bH2l = (u16*)(wsp + 46 * MB);
    u16* h1ph = (u16*)(wsp + 48 * MB);  u16* h1pl = (u16*)(wsp + 52 * MB);
    u16* h2ph = (u16*)(wsp + 24 * MB);  u16* h2pl = (u16*)(wsp + 32 * MB);

    embed_pl<<<dim3(TOK), dim3(256), 0, stream>>>(c_data, ca_data, c_emb, ca_emb,
                                                  x0ph, x0pl, yph, ypl);

    for (int li = 0; li < 6; ++li) {
        int pos = (li != 2 && li != 4);
        int m0 = (li == 3 || li == 5);

        wsplit_layer<<<dim3(pos ? 704 : 192), dim3(256), 0, stream>>>(
            Wk + (size_t)li * DIM * DIM, Wv + (size_t)li * DIM * DIM,
            Wo + (size_t)li * DIM * DIM,
            W1 + (size_t)li * DIM * FFD, W2 + (size_t)li * FFD * DIM,
            btQVh, btQVl, btWoh, btWol, btW1h, btW1l, btW2h, btW2l);

        const u16 *Kph, *Kpl;
        const u16 *residH, *residL; u16 *outH, *outL;
        if (li == 0 || li == 1) {
            // qv fused (A=y, V->Vt direct) + k (A=x0) in one dual-slot launch
            GD dqv = mkgd(yph, ypl, btQVh, btQVl, DIM, DIM, 0,
                          bk + li * DIM, bv + li * DIM, 1024, EP_PL | EP_QV | EP_VT,
                          nullptr, qphh, qpll, Vth, Vtl);
            GD dk = mkgd(x0ph, x0pl, btQVh, btQVl, DIM, DIM, 0,
                         bk + li * DIM, nullptr, DIM, EP_PL,
                         nullptr, kphh, kpll, nullptr, nullptr);
            run_gemm2(dqv, dk, stream);
            Kph = kphh; Kpl = kpll;
            residH = yph; residL = ypl; outH = yph; outL = ypl;
        } else if (li == 2 || li == 4) {
            const u16* ah = (li == 2) ? x0ph : xph;
            const u16* al = (li == 2) ? x0pl : xpl;
            GD dqv = mkgd(ah, al, btQVh, btQVl, DIM, DIM, 0,
                          bk + li * DIM, bv + li * DIM, 1024, EP_PL | EP_QV | EP_VT,
                          nullptr, qphh, qpll, Vth, Vtl);
            run_gemm1(dqv, stream);
            Kph = qphh; Kpl = qpll;
            residH = (li == 2) ? x0ph : xph; residL = (li == 2) ? x0pl : xpl;
            outH = xph; outL = xpl;
        } else {
            // q (A=x) + v (A=y, V->Vt direct) dual-slot
            GD dq = mkgd(xph, xpl, btQVh, btQVl, DIM, DIM, 0,
                         bk + li * DIM, nullptr, DIM, EP_PL,
                         nullptr, qphh, qpll, nullptr, nullptr);
            GD dv = mkgd(yph, ypl, btQVh + 512 * 512, btQVl + 512 * 512, DIM, DIM, 0,
                         bv + li * DIM, nullptr, DIM, EP_VT,
                         nullptr, nullptr, nullptr, Vth, Vtl);
            run_gemm2(dq, dv, stream);
            Kph = qphh; Kpl = qpll;
            residH = xph; residL = xpl; outH = xph; outL = xpl;
        }

        attn_mf<<<dim3(64, 8, 1), dim3(256), 0, stream>>>(
            qphh, qpll, Kph, Kpl, Vth, Vtl, gammas + li * NHEAD, vphh, vpll, m0);

        GD dwo = mkgd(vphh, vpll, btWoh, btWol, DIM, DIM, 0,
                      bo + li * DIM, nullptr, DIM, EP_F32,
                      t1, nullptr, nullptr, nullptr, nullptr);
        run_gemm1(dwo, stream);
        add_ln_pl<<<dim3(TOK / 4), dim3(256), 0, stream>>>(residH, residL, t1,
                                                           ln1s + li * DIM, ln1b + li * DIM,
                                                           outH, outL);
        if (pos) {
            for (int c = 0; c < 2; ++c) {
                GD d1c = mkgd(outH, outL,
                              btW1h + (size_t)c * 1024 * DIM, btW1l + (size_t)c * 1024 * DIM,
                              DIM, DIM, 0, b1 + li * FFD + c * 1024, nullptr,
                              1024, EP_RELU | EP_PL, nullptr, ffh, ffl, nullptr, nullptr);
                run_gemm1(d1c, stream);
                GD d2c = mkgd(ffh, ffl, btW2h, btW2l, 1024, FFD, c * 1024,
                              b2 + li * DIM, nullptr, DIM,
                              (c == 0) ? EP_F32 : (EP_F32 | EP_ACC),
                              t1, nullptr, nullptr, nullptr, nullptr);
                run_gemm1(d2c, stream);
            }
            add_ln_pl<<<dim3(TOK / 4), dim3(256), 0, stream>>>(outH, outL, t1,
                                                               ln2s + li * DIM, ln2b + li * DIM,
                                                               outH, outL);
        }
    }

    concat_pl<<<dim3(TOK), dim3(256), 0, stream>>>(xph, xpl, x0ph, x0pl, hch, hcl);
    wsplit_head<<<dim3(512), dim3(256), 0, stream>>>(oW0, oW1, oW2,
                                                     bH0h, bH0l, bH1h, bH1l, bH2h, bH2l);
    GD g0 = mkgd(hch, hcl, bH0h, bH0l, 1024, 1024, 0, ob0, nullptr, 512,
                 EP_RELU | EP_PL, nullptr, h1ph, h1pl, nullptr, nullptr);
    run_gemm1(g0, stream);
    GD g1 = mkgd(h1ph, h1pl, bH1h, bH1l, 512, 512, 0, ob1, nullptr, 1024,
                 EP_RELU | EP_PL, nullptr, h2ph, h2pl, nullptr, nullptr);
    run_gemm1(g1, stream);
    GD g2 = mkgd(h2ph, h2pl, bH2h, bH2l, 1024, 1024, 0, ob2, nullptr, 1000,
                 EP_F32, out, nullptr, nullptr, nullptr, nullptr);
    run_gemm1(g2, stream);
}